// Round 13
// baseline (232.751 us; speedup 1.0000x reference)
//
#include <hip/hip_runtime.h>
#include <hip/hip_bf16.h>
#include <math.h>

typedef __bf16 bf16;
typedef __bf16 bf16x4 __attribute__((ext_vector_type(4)));
typedef __bf16 bf16x8 __attribute__((ext_vector_type(8)));
typedef float  f32x4  __attribute__((ext_vector_type(4)));
typedef unsigned u32x2 __attribute__((ext_vector_type(2)));
typedef unsigned u32x4 __attribute__((ext_vector_type(4)));

#define T_SEQ 2048
#define E_DIM 1024
#define H_NUM 16
#define D_DIM 64
#define NDELTA 4095
#define PB_STRIDE 4100
#define LOG2E 1.4426950408889634f

__device__ __forceinline__ void gld16(const bf16* g, bf16* l) {
  __builtin_amdgcn_global_load_lds((__attribute__((address_space(1))) void*)(g),
                                   (__attribute__((address_space(3))) void*)(l), 16, 0, 0);
}

// in-register qd-group exchange via official gfx950 builtins
__device__ __forceinline__ void qswap(unsigned &a, unsigned &b) {
  u32x2 t  = __builtin_amdgcn_permlane32_swap(a, b, false, false);
  u32x2 t2 = __builtin_amdgcn_permlane16_swap(t[0], t[1], false, false);
  a = t2[0]; b = t2[1];
}

// ---------------- fused fp32->bf16 cast + gate (one block per bt row) ----------------
__global__ __launch_bounds__(256)
void cast_gate_kernel(const float* __restrict__ hs, bf16* __restrict__ hsb,
                      const float* __restrict__ gru_w, const float* __restrict__ gru_b,
                      const float* __restrict__ gconst, float* __restrict__ gate)
{
  __shared__ float w[512];
  const int tid = threadIdx.x;
  const int bt  = blockIdx.x;
  w[tid]       = gru_w[tid];
  w[tid + 256] = gru_w[tid + 256];
  __syncthreads();

  const int i = bt * 256 + tid;
  const float4 xv = reinterpret_cast<const float4*>(hs)[i];
  bf16x4 o;
  o[0] = (bf16)xv.x; o[1] = (bf16)xv.y; o[2] = (bf16)xv.z; o[3] = (bf16)xv.w;
  reinterpret_cast<bf16x4*>(hsb)[i] = o;

  const int h  = tid >> 4;
  const int d0 = (tid & 15) * 4;
  float acc[8];
#pragma unroll
  for (int e = 0; e < 8; e++) {
    acc[e] = xv.x * w[e*64+d0] + xv.y * w[e*64+d0+1]
           + xv.z * w[e*64+d0+2] + xv.w * w[e*64+d0+3];
  }
#pragma unroll
  for (int e = 0; e < 8; e++) {
    float v = acc[e];
    v += __shfl_xor(v, 1);
    v += __shfl_xor(v, 2);
    v += __shfl_xor(v, 4);
    v += __shfl_xor(v, 8);
    acc[e] = v;
  }
  if ((tid & 15) == 0) {
    float p0 = acc[0]+acc[1]+acc[2]+acc[3] + gru_b[0]+gru_b[1]+gru_b[2]+gru_b[3];
    float p1 = acc[4]+acc[5]+acc[6]+acc[7] + gru_b[4]+gru_b[5]+gru_b[6]+gru_b[7];
    float ga = 1.0f / (1.0f + expf(-p0));
    float gb = 1.0f / (1.0f + expf(-p1));
    float g = (ga * (gb * gconst[h] - 1.0f) + 2.0f) * LOG2E;
    int bb = bt >> 11;
    int t  = bt & (T_SEQ - 1);
    gate[((size_t)(bb * H_NUM + h)) * T_SEQ + t] = g;
  }
}

// ---------------- weight casts (y=0..3) + 4-phase position-bias table (y=4) ----------------
// Copy p, head h at pbt + (p*16+h)*PB_STRIDE + ((p+1)&3); word j = pb(delta = j-2047).
// Phase offset makes lane (lm&3 == p) f32x4 reads 16B-aligned.
__global__ void cast_w_kernel(const float* __restrict__ q_w, const float* __restrict__ k_w,
                              const float* __restrict__ v_w, const float* __restrict__ o_w,
                              bf16* __restrict__ wcat, bf16* __restrict__ wob,
                              const float* __restrict__ rel_embed, float* __restrict__ pbt) {
  int sel = blockIdx.y;
  int tid = threadIdx.x;
  if (sel == 4) {
    int dd = blockIdx.x * 256 + tid;
    if (blockIdx.x >= 16 || dd >= NDELTA) return;
    int delta = dd - (T_SEQ - 1);
    int bucket = (delta > 0) ? 160 : 0;
    int rel = abs(delta);
    int v;
    if (rel < 80) {
      v = rel;
    } else {
      float rf = (float)(rel < 1 ? 1 : rel);
      float lf = logf(rf / 80.0f) * (80.0f / 2.302585092994046f);
      int lg = 80 + (int)lf;
      v = lg < 159 ? lg : 159;
    }
    bucket += v;
#pragma unroll
    for (int h = 0; h < H_NUM; h++) {
      float val = rel_embed[bucket * H_NUM + h];
#pragma unroll
      for (int p = 0; p < 4; p++)
        pbt[(size_t)(p * 16 + h) * PB_STRIDE + ((p + 1) & 3) + dd] = val;
    }
    return;
  }
  int i = blockIdx.x * 256 + tid;
  const float* src = (sel == 0) ? q_w : (sel == 1) ? k_w : (sel == 2) ? v_w : o_w;
  bf16* dst = (sel < 3) ? (wcat + (size_t)sel * 1048576) : wob;
  const float4 v = reinterpret_cast<const float4*>(src)[i];
  bf16x4 o;
  o[0] = (bf16)v.x; o[1] = (bf16)v.y; o[2] = (bf16)v.z; o[3] = (bf16)v.w;
  reinterpret_cast<bf16x4*>(dst)[i] = o;
}

// ---------------- GEMM v3: BK=64 + both-sides XOR chunk swizzle ----------------
template<int MODE, int N_TOTAL>
__global__ __launch_bounds__(256)
void gemm2_kernel(const bf16* __restrict__ A, const bf16* __restrict__ W,
                  const float* __restrict__ b0, const float* __restrict__ b1,
                  const float* __restrict__ b2, float qalpha,
                  void* __restrict__ out0, void* __restrict__ out1, void* __restrict__ out2)
{
  __shared__ bf16 As[128 * 64];
  __shared__ bf16 Bs[128 * 64];
  const int tid  = threadIdx.x;
  const int lane = tid & 63;
  const int wave = tid >> 6;
  const int m0 = blockIdx.y * 128;
  const int n0 = blockIdx.x * 128;
  const int wm = (wave >> 1) * 64;
  const int wn = (wave & 1) * 64;
  const int qd = lane >> 4;
  const int lm = lane & 15;

  const int srow8  = lane >> 3;
  const int schunk = ((lane & 7) ^ srow8) * 8;
  const bf16* gA = A + (size_t)(m0 + wave * 32 + srow8) * 1024 + schunk;
  const bf16* gB = W + (size_t)(n0 + wave * 32 + srow8) * 1024 + schunk;
  bf16* lA = As + wave * 32 * 64;
  bf16* lB = Bs + wave * 32 * 64;

  f32x4 acc[4][4] = {};
  const int xs = lm & 7;

  for (int k0 = 0; k0 < 1024; k0 += 64) {
#pragma unroll
    for (int j = 0; j < 4; j++) {
      gld16(gA + (size_t)j * 8 * 1024 + k0, lA + j * 8 * 64);
      gld16(gB + (size_t)j * 8 * 1024 + k0, lB + j * 8 * 64);
    }
    __syncthreads();
    bf16x8 af[4][2], bfr[4][2];
#pragma unroll
    for (int i = 0; i < 4; i++) {
#pragma unroll
      for (int kk = 0; kk < 2; kk++) {
        af[i][kk]  = *(const bf16x8*)&As[(wm + i * 16 + lm) * 64 + (((kk * 4 + qd) ^ xs) * 8)];
        bfr[i][kk] = *(const bf16x8*)&Bs[(wn + i * 16 + lm) * 64 + (((kk * 4 + qd) ^ xs) * 8)];
      }
    }
#pragma unroll
    for (int kk = 0; kk < 2; kk++)
#pragma unroll
      for (int im = 0; im < 4; im++)
#pragma unroll
        for (int in = 0; in < 4; in++)
          acc[im][in] = __builtin_amdgcn_mfma_f32_16x16x32_bf16(af[im][kk], bfr[in][kk], acc[im][in], 0, 0, 0);
    __syncthreads();
  }

  const int seg = n0 >> 10;
  const float* bias = (MODE == 0) ? b0 : (seg == 0 ? b0 : (seg == 1 ? b1 : b2));
  const float alpha = (MODE == 1 && seg == 0) ? qalpha : 1.0f;

#pragma unroll
  for (int im = 0; im < 4; im++) {
#pragma unroll
    for (int in = 0; in < 4; in++) {
      const int n  = n0 + wn + in * 16 + lm;
      const int n1 = n & 1023;
      const float bv = bias[n1];
      const int mb = m0 + wm + im * 16 + qd * 4;
      if (MODE == 0) {
        float* o = (float*)out0;
#pragma unroll
        for (int r = 0; r < 4; r++)
          o[(size_t)(mb + r) * 1024 + n1] = acc[im][in][r] + bv;
      } else if (seg == 2) {
        const int bb = mb >> 11;
        const int t  = mb & 2047;
        bf16x4 pk;
#pragma unroll
        for (int r = 0; r < 4; r++) pk[r] = (bf16)(acc[im][in][r] + bv);
        *(bf16x4*)&((bf16*)out2)[((size_t)(bb * 1024 + n1)) * 2048 + t] = pk;
      } else {
        bf16* o = (bf16*)(seg == 0 ? out0 : out1);
#pragma unroll
        for (int r = 0; r < 4; r++)
          o[(size_t)(mb + r) * 1024 + n1] = (bf16)((acc[im][in][r] + bv) * alpha);
      }
    }
  }
}

// ---------------- O-projection GEMM: 64x128 tile -> grid (8,64)=512 blocks (2/CU) ----------------
__global__ __launch_bounds__(256)
void gemm_o_kernel(const bf16* __restrict__ A, const bf16* __restrict__ W,
                   const float* __restrict__ bias, float* __restrict__ out)
{
  __shared__ bf16 As[64 * 32];
  __shared__ bf16 Bs[128 * 32];
  const int tid  = threadIdx.x;
  const int lane = tid & 63;
  const int wave = tid >> 6;
  const int m0 = blockIdx.y * 64;
  const int n0 = blockIdx.x * 128;
  const int wm = (wave >> 1) * 32;
  const int wn = (wave & 1) * 64;
  const int qd = lane >> 4;
  const int lm = lane & 15;

  const int row4 = lane >> 2;
  const int col8 = (lane & 3) * 8;
  const bf16* gA0 = A + (size_t)(m0 + wave * 16 + row4) * 1024 + col8;
  const bf16* gB0 = W + (size_t)(n0 + wave * 32 + row4) * 1024 + col8;
  const bf16* gB1 = gB0 + (size_t)16 * 1024;
  bf16* lA0 = As + wave * 16 * 32;
  bf16* lB0 = Bs + (wave * 2 + 0) * 512;
  bf16* lB1 = Bs + (wave * 2 + 1) * 512;

  f32x4 acc[2][4] = {};

  for (int k0 = 0; k0 < 1024; k0 += 32) {
    gld16(gA0 + k0, lA0);
    gld16(gB0 + k0, lB0);
    gld16(gB1 + k0, lB1);
    __syncthreads();
    bf16x8 af[2], bfr[4];
#pragma unroll
    for (int i = 0; i < 2; i++)
      af[i]  = *(const bf16x8*)&As[(wm + i * 16 + lm) * 32 + qd * 8];
#pragma unroll
    for (int i = 0; i < 4; i++)
      bfr[i] = *(const bf16x8*)&Bs[(wn + i * 16 + lm) * 32 + qd * 8];
#pragma unroll
    for (int im = 0; im < 2; im++)
#pragma unroll
      for (int in = 0; in < 4; in++)
        acc[im][in] = __builtin_amdgcn_mfma_f32_16x16x32_bf16(af[im], bfr[in], acc[im][in], 0, 0, 0);
    __syncthreads();
  }

#pragma unroll
  for (int im = 0; im < 2; im++) {
#pragma unroll
    for (int in = 0; in < 4; in++) {
      const int n  = n0 + wn + in * 16 + lm;
      const float bv = bias[n];
      const int mb = m0 + wm + im * 16 + qd * 4;
#pragma unroll
      for (int r = 0; r < 4; r++)
        out[(size_t)(mb + r) * 1024 + n] = acc[im][in][r] + bv;
    }
  }
}

// ---------------- flash attention v10: parity-split + register position-bias ----------------
// Round-11 structure (8 waves = 4 q-groups x 2 s-parities, LDS super-tile) with
// the pbs LDS gather (4096 scalar b32/block, ~44% of LDS-pipe cycles, the 4-5M
// bank conflicts) replaced by 8 aligned dwordx4 per wave-iter from the 4-phase
// pb table in L2, issued at iter top so L2 latency hides under frag reads + QK.
#define LK 72
#define LKV 136
__global__ __launch_bounds__(512, 4)
void attn3_kernel(const bf16* __restrict__ Qg, const bf16* __restrict__ Kg,
                  const bf16* __restrict__ Vtg, const float* __restrict__ gate,
                  const float* __restrict__ pbt, bf16* __restrict__ ctx)
{
  __shared__ __align__(16) char smem[38912];
  bf16*  Ks  = (bf16*)smem;                 // [128][72]  = 18432 B
  bf16*  Vs  = (bf16*)(smem + 18432);       // [64][136]  = 17408 B (main loop uses 35840)

  const int t0 = blockIdx.x * 128;
  const int h  = blockIdx.y;
  const int b  = blockIdx.z;
  const int tid  = threadIdx.x;
  const int lane = tid & 63;
  const int wave = tid >> 6;        // 0..7
  const int pw = wave & 3;          // q-group (32 rows)
  const int sh = wave >> 2;         // s-parity half (0: rows 0-63, 1: rows 64-127)
  const int qd = lane >> 4;
  const int lm = lane & 15;
  const int sbase = sh * 64;

  // per-lane pb base pointer: word g = (s0+16mb+4qd+r) - (t0+pw*32+nb*16+lm) + 2047,
  // always in [0,4095); phase copy pp=lm&3 at offset (pp+1)&3 makes r=0 16B-aligned.
  const int pp = lm & 3;
  const float* pb_base = pbt + (size_t)(pp * 16 + h) * PB_STRIDE + ((pp + 1) & 3)
                         + 4 * qd + 2047 - t0 - pw * 32 - lm;

  bf16x8 qf[2][2];
  float g[2];
#pragma unroll
  for (int nb = 0; nb < 2; nb++) {
    const int q = t0 + pw * 32 + nb * 16 + lm;
    const bf16* qrow = Qg + (size_t)(b * T_SEQ + q) * E_DIM + h * D_DIM;
    qf[nb][0] = *(const bf16x8*)(qrow + qd * 8);
    qf[nb][1] = *(const bf16x8*)(qrow + 32 + qd * 8);
    g[nb] = gate[((size_t)(b * H_NUM + h)) * T_SEQ + q];
  }

  // staging: 512 threads cover K[128 rows][64 cols] and V[64 rows][128 cols]
  const int kr = tid >> 2;            // 0..127 (s row)
  const int kc = (tid & 3) * 16;      // 0/16/32/48
  const bf16* kgp = Kg + ((size_t)(b * T_SEQ) + kr) * E_DIM + h * D_DIM + kc;
  const int vr = tid >> 3;            // 0..63 (d row)
  const int vc = (tid & 7) * 16;      // 0..112 (s col)
  const bf16* vgp = Vtg + ((size_t)(b * 1024) + h * D_DIM + vr) * T_SEQ + vc;

  {
    bf16x8 a0 = *(const bf16x8*)kgp;
    bf16x8 a1 = *(const bf16x8*)(kgp + 8);
    bf16x8 c0 = *(const bf16x8*)vgp;
    bf16x8 c1 = *(const bf16x8*)(vgp + 8);
    *(bf16x8*)&Ks[kr * LK + kc]     = a0;
    *(bf16x8*)&Ks[kr * LK + kc + 8] = a1;
    *(bf16x8*)&Vs[vr * LKV + vc]     = c0;
    *(bf16x8*)&Vs[vr * LKV + vc + 8] = c1;
  }
  __syncthreads();

  f32x4 o[4][2] = {};
  float li[2] = {0.0f, 0.0f};

  for (int sup = 0; sup < T_SEQ / 128; sup++) {
    const int s0 = sup * 128 + sbase;
    const bool more = (sup + 1 < T_SEQ / 128);

    // position-bias for this super-iter: 8 aligned dwordx4 from L2 (vmem pipe);
    // first use is after 8 ds_read_b128 + 16 MFMA -> latency hidden.
    f32x4 pbv[2][4];
#pragma unroll
    for (int nb = 0; nb < 2; nb++)
#pragma unroll
      for (int mb = 0; mb < 4; mb++)
        pbv[nb][mb] = *(const f32x4*)(pb_base + s0 - nb * 16 + 16 * mb);

    bf16x8 nk0, nk1, nv0, nv1;
    if (more) {
      const bf16* kn = kgp + (size_t)(sup + 1) * 128 * E_DIM;
      const bf16* vn = vgp + (sup + 1) * 128;
      nk0 = *(const bf16x8*)kn; nk1 = *(const bf16x8*)(kn + 8);
      nv0 = *(const bf16x8*)vn; nv1 = *(const bf16x8*)(vn + 8);
    }

    bf16x8 kf[4][2];
#pragma unroll
    for (int mb = 0; mb < 4; mb++) {
      kf[mb][0] = *(const bf16x8*)&Ks[(sbase + 16 * mb + lm) * LK + qd * 8];
      kf[mb][1] = *(const bf16x8*)&Ks[(sbase + 16 * mb + lm) * LK + 32 + qd * 8];
    }

    bf16x8 pf[2][2];
#pragma unroll
    for (int nb = 0; nb < 2; nb++) {
      f32x4 sc[4];
#pragma unroll
      for (int mb = 0; mb < 4; mb++) {
        f32x4 t = {};
        t = __builtin_amdgcn_mfma_f32_16x16x32_bf16(kf[mb][0], qf[nb][0], t, 0, 0, 0);
        t = __builtin_amdgcn_mfma_f32_16x16x32_bf16(kf[mb][1], qf[nb][1], t, 0, 0, 0);
        sc[mb] = t;
      }
      float rs = 0.0f;
      unsigned wlo[4], whi[4];
#pragma unroll
      for (int mb = 0; mb < 4; mb++) {
        bf16x4 pk;
#pragma unroll
        for (int r = 0; r < 4; r++) {
          float p = __builtin_amdgcn_exp2f(sc[mb][r] + g[nb] * pbv[nb][mb][r]);
          rs += p;
          pk[r] = (bf16)p;
        }
        u32x2 pw2 = __builtin_bit_cast(u32x2, pk);
        wlo[mb] = pw2[0]; whi[mb] = pw2[1];
      }
      li[nb] += rs;
      unsigned a0 = wlo[0], b0v = wlo[1], a1 = whi[0], b1v = whi[1];
      qswap(a0, b0v);
      qswap(a1, b1v);
      u32x4 h0; h0[0] = a0; h0[1] = a1; h0[2] = b0v; h0[3] = b1v;
      pf[nb][0] = __builtin_bit_cast(bf16x8, h0);
      unsigned c0 = wlo[2], d0v = wlo[3], c1 = whi[2], d1v = whi[3];
      qswap(c0, d0v);
      qswap(c1, d1v);
      u32x4 h1; h1[0] = c0; h1[1] = c1; h1[2] = d0v; h1[3] = d1v;
      pf[nb][1] = __builtin_bit_cast(bf16x8, h1);
    }

#pragma unroll
    for (int db = 0; db < 4; db++) {
      bf16x8 vf0 = *(const bf16x8*)&Vs[(16 * db + lm) * LKV + sbase + qd * 8];
      bf16x8 vf1 = *(const bf16x8*)&Vs[(16 * db + lm) * LKV + sbase + 32 + qd * 8];
#pragma unroll
      for (int nb = 0; nb < 2; nb++) {
        o[db][nb] = __builtin_amdgcn_mfma_f32_16x16x32_bf16(vf0, pf[nb][0], o[db][nb], 0, 0, 0);
        o[db][nb] = __builtin_amdgcn_mfma_f32_16x16x32_bf16(vf1, pf[nb][1], o[db][nb], 0, 0, 0);
      }
    }
    __syncthreads();   // all frag reads of this super-tile done
    if (more) {
      *(bf16x8*)&Ks[kr * LK + kc]      = nk0;
      *(bf16x8*)&Ks[kr * LK + kc + 8]  = nk1;
      *(bf16x8*)&Vs[vr * LKV + vc]     = nv0;
      *(bf16x8*)&Vs[vr * LKV + vc + 8] = nv1;
    }
    __syncthreads();   // staging writes visible
  }

  // epilogue: merge the two parity halves. K/V LDS is dead -> alias it.
  float* oxf  = (float*)smem;            // [4][64][36]  = 36864 B
  float* lixf = (float*)(smem + 36864);  // [4][64][2]   =  2048 B
  if (sh == 1) {
#pragma unroll
    for (int db = 0; db < 4; db++)
#pragma unroll
      for (int nb = 0; nb < 2; nb++)
        *(f32x4*)&oxf[(pw * 64 + lane) * 36 + (db * 2 + nb) * 4] = o[db][nb];
    lixf[(pw * 64 + lane) * 2 + 0] = li[0];
    lixf[(pw * 64 + lane) * 2 + 1] = li[1];
  }
  __syncthreads();
  if (sh == 0) {
#pragma unroll
    for (int db = 0; db < 4; db++)
#pragma unroll
      for (int nb = 0; nb < 2; nb++)
        o[db][nb] += *(const f32x4*)&oxf[(pw * 64 + lane) * 36 + (db * 2 + nb) * 4];
    li[0] += lixf[(pw * 64 + lane) * 2 + 0];
    li[1] += lixf[(pw * 64 + lane) * 2 + 1];

#pragma unroll
    for (int nb = 0; nb < 2; nb++) {
      li[nb] += __shfl_xor(li[nb], 16);
      li[nb] += __shfl_xor(li[nb], 32);
    }
#pragma unroll
    for (int nb = 0; nb < 2; nb++) {
      const float inv = 1.0f / li[nb];
      const int q = t0 + pw * 32 + nb * 16 + lm;
      bf16* obase = ctx + (size_t)(b * T_SEQ + q) * E_DIM + h * D_DIM + 4 * qd;
#pragma unroll
      for (int db = 0; db < 4; db++) {
        bf16x4 ov;
        ov[0] = (bf16)(o[db][nb][0] * inv); ov[1] = (bf16)(o[db][nb][1] * inv);
        ov[2] = (bf16)(o[db][nb][2] * inv); ov[3] = (bf16)(o[db][nb][3] * inv);
        *(bf16x4*)&obase[16 * db] = ov;
      }
    }
  }
}

// ---------------- orchestration ----------------
extern "C" void kernel_launch(void* const* d_in, const int* in_sizes, int n_in,
                              void* d_out, int out_size, void* d_ws, size_t ws_size,
                              hipStream_t stream)
{
  const float* hs     = (const float*)d_in[0];
  const float* q_w    = (const float*)d_in[1];
  const float* q_b    = (const float*)d_in[2];
  const float* k_w    = (const float*)d_in[3];
  const float* k_b    = (const float*)d_in[4];
  const float* v_w    = (const float*)d_in[5];
  const float* v_b    = (const float*)d_in[6];
  const float* out_w  = (const float*)d_in[7];
  const float* out_b  = (const float*)d_in[8];
  const float* rel    = (const float*)d_in[9];
  const float* gconst = (const float*)d_in[10];
  const float* gru_w  = (const float*)d_in[11];
  const float* gru_b  = (const float*)d_in[12];

  char* p = (char*)d_ws;
  bf16* hsb  = (bf16*)p; p += (size_t)4096 * 1024 * 2;
  bf16* wcat = (bf16*)p; p += (size_t)3072 * 1024 * 2;
  bf16* wob  = (bf16*)p; p += (size_t)1024 * 1024 * 2;
  bf16* Qb   = (bf16*)p; p += (size_t)4096 * 1024 * 2;
  bf16* Kb   = (bf16*)p; p += (size_t)4096 * 1024 * 2;
  bf16* Vtb  = (bf16*)p; p += (size_t)2048 * 2048 * 2;
  bf16* ctxb = (bf16*)p; p += (size_t)4096 * 1024 * 2;
  float* gatep = (float*)p; p += (size_t)2 * H_NUM * T_SEQ * 4;
  float* pbt   = (float*)p; p += (size_t)4 * H_NUM * PB_STRIDE * 4;

  cast_gate_kernel<<<4096, 256, 0, stream>>>(hs, hsb, gru_w, gru_b, gconst, gatep);
  cast_w_kernel<<<dim3(1024, 5), 256, 0, stream>>>(q_w, k_w, v_w, out_w, wcat, wob, rel, pbt);

  const float qalpha = 0.125f * LOG2E;
  gemm2_kernel<1, 3072><<<dim3(24, 32), 256, 0, stream>>>(
      hsb, wcat, q_b, k_b, v_b, qalpha, Qb, Kb, Vtb);

  attn3_kernel<<<dim3(T_SEQ / 128, H_NUM, 2), 512, 0, stream>>>(Qb, Kb, Vtb, gatep, pbt, ctxb);

  gemm_o_kernel<<<dim3(8, 64), 256, 0, stream>>>(ctxb, wob, out_b, (float*)d_out);
}

// Round 14
// 217.094 us; speedup vs baseline: 1.0721x; 1.0721x over previous
//
#include <hip/hip_runtime.h>
#include <hip/hip_bf16.h>
#include <math.h>

typedef __bf16 bf16;
typedef __bf16 bf16x4 __attribute__((ext_vector_type(4)));
typedef __bf16 bf16x8 __attribute__((ext_vector_type(8)));
typedef float  f32x4  __attribute__((ext_vector_type(4)));
typedef unsigned u32x2 __attribute__((ext_vector_type(2)));
typedef unsigned u32x4 __attribute__((ext_vector_type(4)));

#define T_SEQ 2048
#define E_DIM 1024
#define H_NUM 16
#define D_DIM 64
#define NDELTA 4095
#define LOG2E 1.4426950408889634f

__device__ __forceinline__ void gld16(const bf16* g, bf16* l) {
  __builtin_amdgcn_global_load_lds((__attribute__((address_space(1))) void*)(g),
                                   (__attribute__((address_space(3))) void*)(l), 16, 0, 0);
}

// in-register qd-group exchange via official gfx950 builtins
__device__ __forceinline__ void qswap(unsigned &a, unsigned &b) {
  u32x2 t  = __builtin_amdgcn_permlane32_swap(a, b, false, false);
  u32x2 t2 = __builtin_amdgcn_permlane16_swap(t[0], t[1], false, false);
  a = t2[0]; b = t2[1];
}

// ---------------- fused fp32->bf16 cast + gate (one block per bt row) ----------------
__global__ __launch_bounds__(256)
void cast_gate_kernel(const float* __restrict__ hs, bf16* __restrict__ hsb,
                      const float* __restrict__ gru_w, const float* __restrict__ gru_b,
                      const float* __restrict__ gconst, float* __restrict__ gate)
{
  __shared__ float w[512];
  const int tid = threadIdx.x;
  const int bt  = blockIdx.x;
  w[tid]       = gru_w[tid];
  w[tid + 256] = gru_w[tid + 256];
  __syncthreads();

  const int i = bt * 256 + tid;
  const float4 xv = reinterpret_cast<const float4*>(hs)[i];
  bf16x4 o;
  o[0] = (bf16)xv.x; o[1] = (bf16)xv.y; o[2] = (bf16)xv.z; o[3] = (bf16)xv.w;
  reinterpret_cast<bf16x4*>(hsb)[i] = o;

  const int h  = tid >> 4;
  const int d0 = (tid & 15) * 4;
  float acc[8];
#pragma unroll
  for (int e = 0; e < 8; e++) {
    acc[e] = xv.x * w[e*64+d0] + xv.y * w[e*64+d0+1]
           + xv.z * w[e*64+d0+2] + xv.w * w[e*64+d0+3];
  }
#pragma unroll
  for (int e = 0; e < 8; e++) {
    float v = acc[e];
    v += __shfl_xor(v, 1);
    v += __shfl_xor(v, 2);
    v += __shfl_xor(v, 4);
    v += __shfl_xor(v, 8);
    acc[e] = v;
  }
  if ((tid & 15) == 0) {
    float p0 = acc[0]+acc[1]+acc[2]+acc[3] + gru_b[0]+gru_b[1]+gru_b[2]+gru_b[3];
    float p1 = acc[4]+acc[5]+acc[6]+acc[7] + gru_b[4]+gru_b[5]+gru_b[6]+gru_b[7];
    float ga = 1.0f / (1.0f + expf(-p0));
    float gb = 1.0f / (1.0f + expf(-p1));
    float g = (ga * (gb * gconst[h] - 1.0f) + 2.0f) * LOG2E;
    int bb = bt >> 11;
    int t  = bt & (T_SEQ - 1);
    gate[((size_t)(bb * H_NUM + h)) * T_SEQ + t] = g;
  }
}

// ---------------- weight casts (y=0..3) + position-bias table (y=4) ----------------
__global__ void cast_w_kernel(const float* __restrict__ q_w, const float* __restrict__ k_w,
                              const float* __restrict__ v_w, const float* __restrict__ o_w,
                              bf16* __restrict__ wcat, bf16* __restrict__ wob,
                              const float* __restrict__ rel_embed, float* __restrict__ pbt) {
  int sel = blockIdx.y;
  int tid = threadIdx.x;
  if (sel == 4) {
    int dd = blockIdx.x * 256 + tid;
    if (blockIdx.x >= 16 || dd >= NDELTA) return;
    int delta = dd - (T_SEQ - 1);
    int bucket = (delta > 0) ? 160 : 0;
    int rel = abs(delta);
    int v;
    if (rel < 80) {
      v = rel;
    } else {
      float rf = (float)(rel < 1 ? 1 : rel);
      float lf = logf(rf / 80.0f) * (80.0f / 2.302585092994046f);
      int lg = 80 + (int)lf;
      v = lg < 159 ? lg : 159;
    }
    bucket += v;
#pragma unroll
    for (int h = 0; h < H_NUM; h++)
      pbt[h * NDELTA + dd] = rel_embed[bucket * H_NUM + h];
    return;
  }
  int i = blockIdx.x * 256 + tid;
  const float* src = (sel == 0) ? q_w : (sel == 1) ? k_w : (sel == 2) ? v_w : o_w;
  bf16* dst = (sel < 3) ? (wcat + (size_t)sel * 1048576) : wob;
  const float4 v = reinterpret_cast<const float4*>(src)[i];
  bf16x4 o;
  o[0] = (bf16)v.x; o[1] = (bf16)v.y; o[2] = (bf16)v.z; o[3] = (bf16)v.w;
  reinterpret_cast<bf16x4*>(dst)[i] = o;
}

// ---------------- GEMM v3: BK=64 + both-sides XOR chunk swizzle ----------------
template<int MODE, int N_TOTAL>
__global__ __launch_bounds__(256)
void gemm2_kernel(const bf16* __restrict__ A, const bf16* __restrict__ W,
                  const float* __restrict__ b0, const float* __restrict__ b1,
                  const float* __restrict__ b2, float qalpha,
                  void* __restrict__ out0, void* __restrict__ out1, void* __restrict__ out2)
{
  __shared__ bf16 As[128 * 64];
  __shared__ bf16 Bs[128 * 64];
  const int tid  = threadIdx.x;
  const int lane = tid & 63;
  const int wave = tid >> 6;
  const int m0 = blockIdx.y * 128;
  const int n0 = blockIdx.x * 128;
  const int wm = (wave >> 1) * 64;
  const int wn = (wave & 1) * 64;
  const int qd = lane >> 4;
  const int lm = lane & 15;

  const int srow8  = lane >> 3;
  const int schunk = ((lane & 7) ^ srow8) * 8;
  const bf16* gA = A + (size_t)(m0 + wave * 32 + srow8) * 1024 + schunk;
  const bf16* gB = W + (size_t)(n0 + wave * 32 + srow8) * 1024 + schunk;
  bf16* lA = As + wave * 32 * 64;
  bf16* lB = Bs + wave * 32 * 64;

  f32x4 acc[4][4] = {};
  const int xs = lm & 7;

  for (int k0 = 0; k0 < 1024; k0 += 64) {
#pragma unroll
    for (int j = 0; j < 4; j++) {
      gld16(gA + (size_t)j * 8 * 1024 + k0, lA + j * 8 * 64);
      gld16(gB + (size_t)j * 8 * 1024 + k0, lB + j * 8 * 64);
    }
    __syncthreads();
    bf16x8 af[4][2], bfr[4][2];
#pragma unroll
    for (int i = 0; i < 4; i++) {
#pragma unroll
      for (int kk = 0; kk < 2; kk++) {
        af[i][kk]  = *(const bf16x8*)&As[(wm + i * 16 + lm) * 64 + (((kk * 4 + qd) ^ xs) * 8)];
        bfr[i][kk] = *(const bf16x8*)&Bs[(wn + i * 16 + lm) * 64 + (((kk * 4 + qd) ^ xs) * 8)];
      }
    }
#pragma unroll
    for (int kk = 0; kk < 2; kk++)
#pragma unroll
      for (int im = 0; im < 4; im++)
#pragma unroll
        for (int in = 0; in < 4; in++)
          acc[im][in] = __builtin_amdgcn_mfma_f32_16x16x32_bf16(af[im][kk], bfr[in][kk], acc[im][in], 0, 0, 0);
    __syncthreads();
  }

  const int seg = n0 >> 10;
  const float* bias = (MODE == 0) ? b0 : (seg == 0 ? b0 : (seg == 1 ? b1 : b2));
  const float alpha = (MODE == 1 && seg == 0) ? qalpha : 1.0f;

#pragma unroll
  for (int im = 0; im < 4; im++) {
#pragma unroll
    for (int in = 0; in < 4; in++) {
      const int n  = n0 + wn + in * 16 + lm;
      const int n1 = n & 1023;
      const float bv = bias[n1];
      const int mb = m0 + wm + im * 16 + qd * 4;
      if (MODE == 0) {
        float* o = (float*)out0;
#pragma unroll
        for (int r = 0; r < 4; r++)
          o[(size_t)(mb + r) * 1024 + n1] = acc[im][in][r] + bv;
      } else if (seg == 2) {
        const int bb = mb >> 11;
        const int t  = mb & 2047;
        bf16x4 pk;
#pragma unroll
        for (int r = 0; r < 4; r++) pk[r] = (bf16)(acc[im][in][r] + bv);
        *(bf16x4*)&((bf16*)out2)[((size_t)(bb * 1024 + n1)) * 2048 + t] = pk;
      } else {
        bf16* o = (bf16*)(seg == 0 ? out0 : out1);
#pragma unroll
        for (int r = 0; r < 4; r++)
          o[(size_t)(mb + r) * 1024 + n1] = (bf16)((acc[im][in][r] + bv) * alpha);
      }
    }
  }
}

// ---------------- O-projection GEMM: 64x128 tile -> grid (8,64)=512 blocks (2/CU) ----------------
__global__ __launch_bounds__(256)
void gemm_o_kernel(const bf16* __restrict__ A, const bf16* __restrict__ W,
                   const float* __restrict__ bias, float* __restrict__ out)
{
  __shared__ bf16 As[64 * 32];
  __shared__ bf16 Bs[128 * 32];
  const int tid  = threadIdx.x;
  const int lane = tid & 63;
  const int wave = tid >> 6;
  const int m0 = blockIdx.y * 64;
  const int n0 = blockIdx.x * 128;
  const int wm = (wave >> 1) * 32;
  const int wn = (wave & 1) * 64;
  const int qd = lane >> 4;
  const int lm = lane & 15;

  const int row4 = lane >> 2;
  const int col8 = (lane & 3) * 8;
  const bf16* gA0 = A + (size_t)(m0 + wave * 16 + row4) * 1024 + col8;
  const bf16* gB0 = W + (size_t)(n0 + wave * 32 + row4) * 1024 + col8;
  const bf16* gB1 = gB0 + (size_t)16 * 1024;
  bf16* lA0 = As + wave * 16 * 32;
  bf16* lB0 = Bs + (wave * 2 + 0) * 512;
  bf16* lB1 = Bs + (wave * 2 + 1) * 512;

  f32x4 acc[2][4] = {};

  for (int k0 = 0; k0 < 1024; k0 += 32) {
    gld16(gA0 + k0, lA0);
    gld16(gB0 + k0, lB0);
    gld16(gB1 + k0, lB1);
    __syncthreads();
    bf16x8 af[2], bfr[4];
#pragma unroll
    for (int i = 0; i < 2; i++)
      af[i]  = *(const bf16x8*)&As[(wm + i * 16 + lm) * 32 + qd * 8];
#pragma unroll
    for (int i = 0; i < 4; i++)
      bfr[i] = *(const bf16x8*)&Bs[(wn + i * 16 + lm) * 32 + qd * 8];
#pragma unroll
    for (int im = 0; im < 2; im++)
#pragma unroll
      for (int in = 0; in < 4; in++)
        acc[im][in] = __builtin_amdgcn_mfma_f32_16x16x32_bf16(af[im], bfr[in], acc[im][in], 0, 0, 0);
    __syncthreads();
  }

#pragma unroll
  for (int im = 0; im < 2; im++) {
#pragma unroll
    for (int in = 0; in < 4; in++) {
      const int n  = n0 + wn + in * 16 + lm;
      const float bv = bias[n];
      const int mb = m0 + wm + im * 16 + qd * 4;
#pragma unroll
      for (int r = 0; r < 4; r++)
        out[(size_t)(mb + r) * 1024 + n] = acc[im][in][r] + bv;
    }
  }
}

// ---------------- flash attention v7: 8 waves/block (16 q-rows per wave) ----------------
// Best measured configuration (round 9: attn 62.2 us, total 217.1 us).
#define LK 72
__global__ __launch_bounds__(512)
void attn3_kernel(const bf16* __restrict__ Qg, const bf16* __restrict__ Kg,
                  const bf16* __restrict__ Vtg, const float* __restrict__ gate,
                  const float* __restrict__ pbt, bf16* __restrict__ ctx)
{
  __shared__ bf16 Ks[2][64 * LK];
  __shared__ bf16 Vs[2][64 * LK];
  __shared__ float pbs[2176];

  const int t0 = blockIdx.x * 128;
  const int h  = blockIdx.y;
  const int b  = blockIdx.z;
  const int tid  = threadIdx.x;
  const int lane = tid & 63;
  const int wave = tid >> 6;        // 0..7
  const int qd = lane >> 4;
  const int lm = lane & 15;

  for (int i = tid; i < 2176; i += 512) {
    int idx = i - t0 + 1920;
    pbs[i] = (idx >= 0 && idx < NDELTA) ? pbt[h * NDELTA + idx] : 0.0f;
  }

  // each wave owns 16 q-rows: q = t0 + wave*16 + lm
  const int rowoff = wave * 16 + lm;
  bf16x8 qf[2];
  float g;
  {
    const int q = t0 + rowoff;
    const bf16* qrow = Qg + (size_t)(b * T_SEQ + q) * E_DIM + h * D_DIM;
    qf[0] = *(const bf16x8*)(qrow + qd * 8);
    qf[1] = *(const bf16x8*)(qrow + 32 + qd * 8);
    g = gate[((size_t)(b * H_NUM + h)) * T_SEQ + q];
  }

  // staging: 512 threads, each 1 bf16x8 chunk of K and of V (64 rows x 64 cols)
  const int srow = tid >> 3;
  const int scol = (tid & 7) * 8;
  const bf16* kgp = Kg  + ((size_t)(b * T_SEQ) + srow) * E_DIM + h * D_DIM + scol;
  const bf16* vgp = Vtg + ((size_t)(b * 1024) + h * D_DIM + srow) * T_SEQ + scol;

  {
    bf16x8 a0 = *(const bf16x8*)kgp;
    bf16x8 c0 = *(const bf16x8*)vgp;
    *(bf16x8*)&Ks[0][srow * LK + scol] = a0;
    *(bf16x8*)&Vs[0][srow * LK + scol] = c0;
  }
  __syncthreads();

  f32x4 o[4] = {};
  float li = 0.0f;

  for (int it = 0; it < T_SEQ / 64; it++) {
    const int s0 = it * 64;
    const int buf = it & 1;
    const bool more = (it + 1 < T_SEQ / 64);
    bf16x8 nk0, nv0;
    if (more) {
      nk0 = *(const bf16x8*)(kgp + (size_t)(s0 + 64) * E_DIM);
      nv0 = *(const bf16x8*)(vgp + (s0 + 64));
    }

    bf16x8 kf[4][2];
#pragma unroll
    for (int mb = 0; mb < 4; mb++) {
      kf[mb][0] = *(const bf16x8*)&Ks[buf][(16 * mb + lm) * LK + qd * 8];
      kf[mb][1] = *(const bf16x8*)&Ks[buf][(16 * mb + lm) * LK + 32 + qd * 8];
    }

    f32x4 sc[4];
#pragma unroll
    for (int mb = 0; mb < 4; mb++) {
      f32x4 t = {};
      t = __builtin_amdgcn_mfma_f32_16x16x32_bf16(kf[mb][0], qf[0], t, 0, 0, 0);
      t = __builtin_amdgcn_mfma_f32_16x16x32_bf16(kf[mb][1], qf[1], t, 0, 0, 0);
      sc[mb] = t;
    }
    const int ib = s0 + 4 * qd + 127 - rowoff;
    float rs = 0.0f;
    unsigned wlo[4], whi[4];
#pragma unroll
    for (int mb = 0; mb < 4; mb++) {
      bf16x4 pk;
#pragma unroll
      for (int r = 0; r < 4; r++) {
        float p = __builtin_amdgcn_exp2f(sc[mb][r] + g * pbs[ib + 16 * mb + r]);
        rs += p;
        pk[r] = (bf16)p;
      }
      u32x2 pw = __builtin_bit_cast(u32x2, pk);
      wlo[mb] = pw[0]; whi[mb] = pw[1];
    }
    li += rs;
    bf16x8 pf[2];
    {
      unsigned a0 = wlo[0], b0v = wlo[1], a1 = whi[0], b1v = whi[1];
      qswap(a0, b0v);
      qswap(a1, b1v);
      u32x4 h0; h0[0] = a0; h0[1] = a1; h0[2] = b0v; h0[3] = b1v;
      pf[0] = __builtin_bit_cast(bf16x8, h0);
      unsigned c0 = wlo[2], d0v = wlo[3], c1 = whi[2], d1v = whi[3];
      qswap(c0, d0v);
      qswap(c1, d1v);
      u32x4 h1; h1[0] = c0; h1[1] = c1; h1[2] = d0v; h1[3] = d1v;
      pf[1] = __builtin_bit_cast(bf16x8, h1);
    }

#pragma unroll
    for (int db = 0; db < 4; db++) {
      bf16x8 vf0 = *(const bf16x8*)&Vs[buf][(16 * db + lm) * LK + qd * 8];
      bf16x8 vf1 = *(const bf16x8*)&Vs[buf][(16 * db + lm) * LK + 32 + qd * 8];
      o[db] = __builtin_amdgcn_mfma_f32_16x16x32_bf16(vf0, pf[0], o[db], 0, 0, 0);
      o[db] = __builtin_amdgcn_mfma_f32_16x16x32_bf16(vf1, pf[1], o[db], 0, 0, 0);
    }
    if (more) {
      *(bf16x8*)&Ks[buf ^ 1][srow * LK + scol] = nk0;
      *(bf16x8*)&Vs[buf ^ 1][srow * LK + scol] = nv0;
    }
    __syncthreads();
  }

  li += __shfl_xor(li, 16);
  li += __shfl_xor(li, 32);
  {
    const float inv = 1.0f / li;
    const int q = t0 + rowoff;
    bf16* obase = ctx + (size_t)(b * T_SEQ + q) * E_DIM + h * D_DIM + 4 * qd;
#pragma unroll
    for (int db = 0; db < 4; db++) {
      bf16x4 ov;
      ov[0] = (bf16)(o[db][0] * inv); ov[1] = (bf16)(o[db][1] * inv);
      ov[2] = (bf16)(o[db][2] * inv); ov[3] = (bf16)(o[db][3] * inv);
      *(bf16x4*)&obase[16 * db] = ov;
    }
  }
}

// ---------------- orchestration ----------------
extern "C" void kernel_launch(void* const* d_in, const int* in_sizes, int n_in,
                              void* d_out, int out_size, void* d_ws, size_t ws_size,
                              hipStream_t stream)
{
  const float* hs     = (const float*)d_in[0];
  const float* q_w    = (const float*)d_in[1];
  const float* q_b    = (const float*)d_in[2];
  const float* k_w    = (const float*)d_in[3];
  const float* k_b    = (const float*)d_in[4];
  const float* v_w    = (const float*)d_in[5];
  const float* v_b    = (const float*)d_in[6];
  const float* out_w  = (const float*)d_in[7];
  const float* out_b  = (const float*)d_in[8];
  const float* rel    = (const float*)d_in[9];
  const float* gconst = (const float*)d_in[10];
  const float* gru_w  = (const float*)d_in[11];
  const float* gru_b  = (const float*)d_in[12];

  char* p = (char*)d_ws;
  bf16* hsb  = (bf16*)p; p += (size_t)4096 * 1024 * 2;
  bf16* wcat = (bf16*)p; p += (size_t)3072 * 1024 * 2;
  bf16* wob  = (bf16*)p; p += (size_t)1024 * 1024 * 2;
  bf16* Qb   = (bf16*)p; p += (size_t)4096 * 1024 * 2;
  bf16* Kb   = (bf16*)p; p += (size_t)4096 * 1024 * 2;
  bf16* Vtb  = (bf16*)p; p += (size_t)2048 * 2048 * 2;
  bf16* ctxb = (bf16*)p; p += (size_t)4096 * 1024 * 2;
  float* gatep = (float*)p; p += (size_t)2 * H_NUM * T_SEQ * 4;
  float* pbt   = (float*)p; p += (size_t)H_NUM * NDELTA * 4;

  cast_gate_kernel<<<4096, 256, 0, stream>>>(hs, hsb, gru_w, gru_b, gconst, gatep);
  cast_w_kernel<<<dim3(1024, 5), 256, 0, stream>>>(q_w, k_w, v_w, out_w, wcat, wob, rel, pbt);

  const float qalpha = 0.125f * LOG2E;
  gemm2_kernel<1, 3072><<<dim3(24, 32), 256, 0, stream>>>(
      hsb, wcat, q_b, k_b, v_b, qalpha, Qb, Kb, Vtb);

  attn3_kernel<<<dim3(T_SEQ / 128, H_NUM, 2), 512, 0, stream>>>(Qb, Kb, Vtb, gatep, pbt, ctxb);

  gemm_o_kernel<<<dim3(8, 64), 256, 0, stream>>>(ctxb, wob, out_b, (float*)d_out);
}

// Round 15
// 216.102 us; speedup vs baseline: 1.0770x; 1.0046x over previous
//
#include <hip/hip_runtime.h>
#include <hip/hip_bf16.h>
#include <math.h>

typedef __bf16 bf16;
typedef __bf16 bf16x4 __attribute__((ext_vector_type(4)));
typedef __bf16 bf16x8 __attribute__((ext_vector_type(8)));
typedef float  f32x4  __attribute__((ext_vector_type(4)));
typedef unsigned u32x2 __attribute__((ext_vector_type(2)));
typedef unsigned u32x4 __attribute__((ext_vector_type(4)));

#define T_SEQ 2048
#define E_DIM 1024
#define H_NUM 16
#define D_DIM 64
#define NDELTA 4095
#define LOG2E 1.4426950408889634f

__device__ __forceinline__ void gld16(const bf16* g, bf16* l) {
  __builtin_amdgcn_global_load_lds((__attribute__((address_space(1))) void*)(g),
                                   (__attribute__((address_space(3))) void*)(l), 16, 0, 0);
}

// in-register qd-group exchange via official gfx950 builtins
__device__ __forceinline__ void qswap(unsigned &a, unsigned &b) {
  u32x2 t  = __builtin_amdgcn_permlane32_swap(a, b, false, false);
  u32x2 t2 = __builtin_amdgcn_permlane16_swap(t[0], t[1], false, false);
  a = t2[0]; b = t2[1];
}

// ---------------- fused fp32->bf16 cast + gate (one block per bt row) ----------------
__global__ __launch_bounds__(256)
void cast_gate_kernel(const float* __restrict__ hs, bf16* __restrict__ hsb,
                      const float* __restrict__ gru_w, const float* __restrict__ gru_b,
                      const float* __restrict__ gconst, float* __restrict__ gate)
{
  __shared__ float w[512];
  const int tid = threadIdx.x;
  const int bt  = blockIdx.x;
  w[tid]       = gru_w[tid];
  w[tid + 256] = gru_w[tid + 256];
  __syncthreads();

  const int i = bt * 256 + tid;
  const float4 xv = reinterpret_cast<const float4*>(hs)[i];
  bf16x4 o;
  o[0] = (bf16)xv.x; o[1] = (bf16)xv.y; o[2] = (bf16)xv.z; o[3] = (bf16)xv.w;
  reinterpret_cast<bf16x4*>(hsb)[i] = o;

  const int h  = tid >> 4;
  const int d0 = (tid & 15) * 4;
  float acc[8];
#pragma unroll
  for (int e = 0; e < 8; e++) {
    acc[e] = xv.x * w[e*64+d0] + xv.y * w[e*64+d0+1]
           + xv.z * w[e*64+d0+2] + xv.w * w[e*64+d0+3];
  }
#pragma unroll
  for (int e = 0; e < 8; e++) {
    float v = acc[e];
    v += __shfl_xor(v, 1);
    v += __shfl_xor(v, 2);
    v += __shfl_xor(v, 4);
    v += __shfl_xor(v, 8);
    acc[e] = v;
  }
  if ((tid & 15) == 0) {
    float p0 = acc[0]+acc[1]+acc[2]+acc[3] + gru_b[0]+gru_b[1]+gru_b[2]+gru_b[3];
    float p1 = acc[4]+acc[5]+acc[6]+acc[7] + gru_b[4]+gru_b[5]+gru_b[6]+gru_b[7];
    float ga = 1.0f / (1.0f + expf(-p0));
    float gb = 1.0f / (1.0f + expf(-p1));
    float g = (ga * (gb * gconst[h] - 1.0f) + 2.0f) * LOG2E;
    int bb = bt >> 11;
    int t  = bt & (T_SEQ - 1);
    gate[((size_t)(bb * H_NUM + h)) * T_SEQ + t] = g;
  }
}

// ---------------- weight casts (y=0..3) + position-bias table (y=4) ----------------
__global__ void cast_w_kernel(const float* __restrict__ q_w, const float* __restrict__ k_w,
                              const float* __restrict__ v_w, const float* __restrict__ o_w,
                              bf16* __restrict__ wcat, bf16* __restrict__ wob,
                              const float* __restrict__ rel_embed, float* __restrict__ pbt) {
  int sel = blockIdx.y;
  int tid = threadIdx.x;
  if (sel == 4) {
    int dd = blockIdx.x * 256 + tid;
    if (blockIdx.x >= 16 || dd >= NDELTA) return;
    int delta = dd - (T_SEQ - 1);
    int bucket = (delta > 0) ? 160 : 0;
    int rel = abs(delta);
    int v;
    if (rel < 80) {
      v = rel;
    } else {
      float rf = (float)(rel < 1 ? 1 : rel);
      float lf = logf(rf / 80.0f) * (80.0f / 2.302585092994046f);
      int lg = 80 + (int)lf;
      v = lg < 159 ? lg : 159;
    }
    bucket += v;
#pragma unroll
    for (int h = 0; h < H_NUM; h++)
      pbt[h * NDELTA + dd] = rel_embed[bucket * H_NUM + h];
    return;
  }
  int i = blockIdx.x * 256 + tid;
  const float* src = (sel == 0) ? q_w : (sel == 1) ? k_w : (sel == 2) ? v_w : o_w;
  bf16* dst = (sel < 3) ? (wcat + (size_t)sel * 1048576) : wob;
  const float4 v = reinterpret_cast<const float4*>(src)[i];
  bf16x4 o;
  o[0] = (bf16)v.x; o[1] = (bf16)v.y; o[2] = (bf16)v.z; o[3] = (bf16)v.w;
  reinterpret_cast<bf16x4*>(dst)[i] = o;
}

// ---------------- GEMM v3: BK=64 + both-sides XOR chunk swizzle ----------------
template<int MODE, int N_TOTAL>
__global__ __launch_bounds__(256)
void gemm2_kernel(const bf16* __restrict__ A, const bf16* __restrict__ W,
                  const float* __restrict__ b0, const float* __restrict__ b1,
                  const float* __restrict__ b2, float qalpha,
                  void* __restrict__ out0, void* __restrict__ out1, void* __restrict__ out2)
{
  __shared__ bf16 As[128 * 64];
  __shared__ bf16 Bs[128 * 64];
  const int tid  = threadIdx.x;
  const int lane = tid & 63;
  const int wave = tid >> 6;
  const int m0 = blockIdx.y * 128;
  const int n0 = blockIdx.x * 128;
  const int wm = (wave >> 1) * 64;
  const int wn = (wave & 1) * 64;
  const int qd = lane >> 4;
  const int lm = lane & 15;

  const int srow8  = lane >> 3;
  const int schunk = ((lane & 7) ^ srow8) * 8;
  const bf16* gA = A + (size_t)(m0 + wave * 32 + srow8) * 1024 + schunk;
  const bf16* gB = W + (size_t)(n0 + wave * 32 + srow8) * 1024 + schunk;
  bf16* lA = As + wave * 32 * 64;
  bf16* lB = Bs + wave * 32 * 64;

  f32x4 acc[4][4] = {};
  const int xs = lm & 7;

  for (int k0 = 0; k0 < 1024; k0 += 64) {
#pragma unroll
    for (int j = 0; j < 4; j++) {
      gld16(gA + (size_t)j * 8 * 1024 + k0, lA + j * 8 * 64);
      gld16(gB + (size_t)j * 8 * 1024 + k0, lB + j * 8 * 64);
    }
    __syncthreads();
    bf16x8 af[4][2], bfr[4][2];
#pragma unroll
    for (int i = 0; i < 4; i++) {
#pragma unroll
      for (int kk = 0; kk < 2; kk++) {
        af[i][kk]  = *(const bf16x8*)&As[(wm + i * 16 + lm) * 64 + (((kk * 4 + qd) ^ xs) * 8)];
        bfr[i][kk] = *(const bf16x8*)&Bs[(wn + i * 16 + lm) * 64 + (((kk * 4 + qd) ^ xs) * 8)];
      }
    }
#pragma unroll
    for (int kk = 0; kk < 2; kk++)
#pragma unroll
      for (int im = 0; im < 4; im++)
#pragma unroll
        for (int in = 0; in < 4; in++)
          acc[im][in] = __builtin_amdgcn_mfma_f32_16x16x32_bf16(af[im][kk], bfr[in][kk], acc[im][in], 0, 0, 0);
    __syncthreads();
  }

  const int seg = n0 >> 10;
  const float* bias = (MODE == 0) ? b0 : (seg == 0 ? b0 : (seg == 1 ? b1 : b2));
  const float alpha = (MODE == 1 && seg == 0) ? qalpha : 1.0f;

#pragma unroll
  for (int im = 0; im < 4; im++) {
#pragma unroll
    for (int in = 0; in < 4; in++) {
      const int n  = n0 + wn + in * 16 + lm;
      const int n1 = n & 1023;
      const float bv = bias[n1];
      const int mb = m0 + wm + im * 16 + qd * 4;
      if (MODE == 0) {
        float* o = (float*)out0;
#pragma unroll
        for (int r = 0; r < 4; r++)
          o[(size_t)(mb + r) * 1024 + n1] = acc[im][in][r] + bv;
      } else if (seg == 2) {
        const int bb = mb >> 11;
        const int t  = mb & 2047;
        bf16x4 pk;
#pragma unroll
        for (int r = 0; r < 4; r++) pk[r] = (bf16)(acc[im][in][r] + bv);
        *(bf16x4*)&((bf16*)out2)[((size_t)(bb * 1024 + n1)) * 2048 + t] = pk;
      } else {
        bf16* o = (bf16*)(seg == 0 ? out0 : out1);
#pragma unroll
        for (int r = 0; r < 4; r++)
          o[(size_t)(mb + r) * 1024 + n1] = (bf16)((acc[im][in][r] + bv) * alpha);
      }
    }
  }
}

// ---------------- O-projection GEMM: 64x128 tile -> grid (8,64)=512 blocks (2/CU) ----------------
__global__ __launch_bounds__(256)
void gemm_o_kernel(const bf16* __restrict__ A, const bf16* __restrict__ W,
                   const float* __restrict__ bias, float* __restrict__ out)
{
  __shared__ bf16 As[64 * 32];
  __shared__ bf16 Bs[128 * 32];
  const int tid  = threadIdx.x;
  const int lane = tid & 63;
  const int wave = tid >> 6;
  const int m0 = blockIdx.y * 64;
  const int n0 = blockIdx.x * 128;
  const int wm = (wave >> 1) * 32;
  const int wn = (wave & 1) * 64;
  const int qd = lane >> 4;
  const int lm = lane & 15;

  const int row4 = lane >> 2;
  const int col8 = (lane & 3) * 8;
  const bf16* gA0 = A + (size_t)(m0 + wave * 16 + row4) * 1024 + col8;
  const bf16* gB0 = W + (size_t)(n0 + wave * 32 + row4) * 1024 + col8;
  const bf16* gB1 = gB0 + (size_t)16 * 1024;
  bf16* lA0 = As + wave * 16 * 32;
  bf16* lB0 = Bs + (wave * 2 + 0) * 512;
  bf16* lB1 = Bs + (wave * 2 + 1) * 512;

  f32x4 acc[2][4] = {};

  for (int k0 = 0; k0 < 1024; k0 += 32) {
    gld16(gA0 + k0, lA0);
    gld16(gB0 + k0, lB0);
    gld16(gB1 + k0, lB1);
    __syncthreads();
    bf16x8 af[2], bfr[4];
#pragma unroll
    for (int i = 0; i < 2; i++)
      af[i]  = *(const bf16x8*)&As[(wm + i * 16 + lm) * 32 + qd * 8];
#pragma unroll
    for (int i = 0; i < 4; i++)
      bfr[i] = *(const bf16x8*)&Bs[(wn + i * 16 + lm) * 32 + qd * 8];
#pragma unroll
    for (int im = 0; im < 2; im++)
#pragma unroll
      for (int in = 0; in < 4; in++)
        acc[im][in] = __builtin_amdgcn_mfma_f32_16x16x32_bf16(af[im], bfr[in], acc[im][in], 0, 0, 0);
    __syncthreads();
  }

#pragma unroll
  for (int im = 0; im < 2; im++) {
#pragma unroll
    for (int in = 0; in < 4; in++) {
      const int n  = n0 + wn + in * 16 + lm;
      const float bv = bias[n];
      const int mb = m0 + wm + im * 16 + qd * 4;
#pragma unroll
      for (int r = 0; r < 4; r++)
        out[(size_t)(mb + r) * 1024 + n] = acc[im][in][r] + bv;
    }
  }
}

// ---------------- flash attention v7 + XCD-chunked block swizzle ----------------
// Round-9 structure (8 waves x 16 q-rows, best measured: attn 61.4 us). Grid is
// flattened to 512 and remapped wid = (w&7)*64 + (w>>3) (bijective, 512=8*64):
// XCD p hosts work-ids p*64..p*64+63 = 4 complete (h,b) groups, so the 16 blocks
// sharing a (h,b)'s 512 KB K/V land on ONE XCD L2 (2 MB/XCD, fits 4 MB) instead
// of being round-robined across all 8 (the ~45 MB FETCH over-fetch).
#define LK 72
__global__ __launch_bounds__(512)
void attn3_kernel(const bf16* __restrict__ Qg, const bf16* __restrict__ Kg,
                  const bf16* __restrict__ Vtg, const float* __restrict__ gate,
                  const float* __restrict__ pbt, bf16* __restrict__ ctx)
{
  __shared__ bf16 Ks[2][64 * LK];
  __shared__ bf16 Vs[2][64 * LK];
  __shared__ float pbs[2176];

  const int wid0 = blockIdx.x;                       // 0..511 (hw linear)
  const int wid  = ((wid0 & 7) << 6) | (wid0 >> 3);  // XCD-chunked remap
  const int t0 = (wid & 15) * 128;
  const int h  = (wid >> 4) & 15;
  const int b  = wid >> 8;
  const int tid  = threadIdx.x;
  const int lane = tid & 63;
  const int wave = tid >> 6;        // 0..7
  const int qd = lane >> 4;
  const int lm = lane & 15;

  for (int i = tid; i < 2176; i += 512) {
    int idx = i - t0 + 1920;
    pbs[i] = (idx >= 0 && idx < NDELTA) ? pbt[h * NDELTA + idx] : 0.0f;
  }

  // each wave owns 16 q-rows: q = t0 + wave*16 + lm
  const int rowoff = wave * 16 + lm;
  bf16x8 qf[2];
  float g;
  {
    const int q = t0 + rowoff;
    const bf16* qrow = Qg + (size_t)(b * T_SEQ + q) * E_DIM + h * D_DIM;
    qf[0] = *(const bf16x8*)(qrow + qd * 8);
    qf[1] = *(const bf16x8*)(qrow + 32 + qd * 8);
    g = gate[((size_t)(b * H_NUM + h)) * T_SEQ + q];
  }

  // staging: 512 threads, each 1 bf16x8 chunk of K and of V (64 rows x 64 cols)
  const int srow = tid >> 3;
  const int scol = (tid & 7) * 8;
  const bf16* kgp = Kg  + ((size_t)(b * T_SEQ) + srow) * E_DIM + h * D_DIM + scol;
  const bf16* vgp = Vtg + ((size_t)(b * 1024) + h * D_DIM + srow) * T_SEQ + scol;

  {
    bf16x8 a0 = *(const bf16x8*)kgp;
    bf16x8 c0 = *(const bf16x8*)vgp;
    *(bf16x8*)&Ks[0][srow * LK + scol] = a0;
    *(bf16x8*)&Vs[0][srow * LK + scol] = c0;
  }
  __syncthreads();

  f32x4 o[4] = {};
  float li = 0.0f;

  for (int it = 0; it < T_SEQ / 64; it++) {
    const int s0 = it * 64;
    const int buf = it & 1;
    const bool more = (it + 1 < T_SEQ / 64);
    bf16x8 nk0, nv0;
    if (more) {
      nk0 = *(const bf16x8*)(kgp + (size_t)(s0 + 64) * E_DIM);
      nv0 = *(const bf16x8*)(vgp + (s0 + 64));
    }

    bf16x8 kf[4][2];
#pragma unroll
    for (int mb = 0; mb < 4; mb++) {
      kf[mb][0] = *(const bf16x8*)&Ks[buf][(16 * mb + lm) * LK + qd * 8];
      kf[mb][1] = *(const bf16x8*)&Ks[buf][(16 * mb + lm) * LK + 32 + qd * 8];
    }

    f32x4 sc[4];
#pragma unroll
    for (int mb = 0; mb < 4; mb++) {
      f32x4 t = {};
      t = __builtin_amdgcn_mfma_f32_16x16x32_bf16(kf[mb][0], qf[0], t, 0, 0, 0);
      t = __builtin_amdgcn_mfma_f32_16x16x32_bf16(kf[mb][1], qf[1], t, 0, 0, 0);
      sc[mb] = t;
    }
    const int ib = s0 + 4 * qd + 127 - rowoff;
    float rs = 0.0f;
    unsigned wlo[4], whi[4];
#pragma unroll
    for (int mb = 0; mb < 4; mb++) {
      bf16x4 pk;
#pragma unroll
      for (int r = 0; r < 4; r++) {
        float p = __builtin_amdgcn_exp2f(sc[mb][r] + g * pbs[ib + 16 * mb + r]);
        rs += p;
        pk[r] = (bf16)p;
      }
      u32x2 pw = __builtin_bit_cast(u32x2, pk);
      wlo[mb] = pw[0]; whi[mb] = pw[1];
    }
    li += rs;
    bf16x8 pf[2];
    {
      unsigned a0 = wlo[0], b0v = wlo[1], a1 = whi[0], b1v = whi[1];
      qswap(a0, b0v);
      qswap(a1, b1v);
      u32x4 h0; h0[0] = a0; h0[1] = a1; h0[2] = b0v; h0[3] = b1v;
      pf[0] = __builtin_bit_cast(bf16x8, h0);
      unsigned c0 = wlo[2], d0v = wlo[3], c1 = whi[2], d1v = whi[3];
      qswap(c0, d0v);
      qswap(c1, d1v);
      u32x4 h1; h1[0] = c0; h1[1] = c1; h1[2] = d0v; h1[3] = d1v;
      pf[1] = __builtin_bit_cast(bf16x8, h1);
    }

#pragma unroll
    for (int db = 0; db < 4; db++) {
      bf16x8 vf0 = *(const bf16x8*)&Vs[buf][(16 * db + lm) * LK + qd * 8];
      bf16x8 vf1 = *(const bf16x8*)&Vs[buf][(16 * db + lm) * LK + 32 + qd * 8];
      o[db] = __builtin_amdgcn_mfma_f32_16x16x32_bf16(vf0, pf[0], o[db], 0, 0, 0);
      o[db] = __builtin_amdgcn_mfma_f32_16x16x32_bf16(vf1, pf[1], o[db], 0, 0, 0);
    }
    if (more) {
      *(bf16x8*)&Ks[buf ^ 1][srow * LK + scol] = nk0;
      *(bf16x8*)&Vs[buf ^ 1][srow * LK + scol] = nv0;
    }
    __syncthreads();
  }

  li += __shfl_xor(li, 16);
  li += __shfl_xor(li, 32);
  {
    const float inv = 1.0f / li;
    const int q = t0 + rowoff;
    bf16* obase = ctx + (size_t)(b * T_SEQ + q) * E_DIM + h * D_DIM + 4 * qd;
#pragma unroll
    for (int db = 0; db < 4; db++) {
      bf16x4 ov;
      ov[0] = (bf16)(o[db][0] * inv); ov[1] = (bf16)(o[db][1] * inv);
      ov[2] = (bf16)(o[db][2] * inv); ov[3] = (bf16)(o[db][3] * inv);
      *(bf16x4*)&obase[16 * db] = ov;
    }
  }
}

// ---------------- orchestration ----------------
extern "C" void kernel_launch(void* const* d_in, const int* in_sizes, int n_in,
                              void* d_out, int out_size, void* d_ws, size_t ws_size,
                              hipStream_t stream)
{
  const float* hs     = (const float*)d_in[0];
  const float* q_w    = (const float*)d_in[1];
  const float* q_b    = (const float*)d_in[2];
  const float* k_w    = (const float*)d_in[3];
  const float* k_b    = (const float*)d_in[4];
  const float* v_w    = (const float*)d_in[5];
  const float* v_b    = (const float*)d_in[6];
  const float* out_w  = (const float*)d_in[7];
  const float* out_b  = (const float*)d_in[8];
  const float* rel    = (const float*)d_in[9];
  const float* gconst = (const float*)d_in[10];
  const float* gru_w  = (const float*)d_in[11];
  const float* gru_b  = (const float*)d_in[12];

  char* p = (char*)d_ws;
  bf16* hsb  = (bf16*)p; p += (size_t)4096 * 1024 * 2;
  bf16* wcat = (bf16*)p; p += (size_t)3072 * 1024 * 2;
  bf16* wob  = (bf16*)p; p += (size_t)1024 * 1024 * 2;
  bf16* Qb   = (bf16*)p; p += (size_t)4096 * 1024 * 2;
  bf16* Kb   = (bf16*)p; p += (size_t)4096 * 1024 * 2;
  bf16* Vtb  = (bf16*)p; p += (size_t)2048 * 2048 * 2;
  bf16* ctxb = (bf16*)p; p += (size_t)4096 * 1024 * 2;
  float* gatep = (float*)p; p += (size_t)2 * H_NUM * T_SEQ * 4;
  float* pbt   = (float*)p; p += (size_t)H_NUM * NDELTA * 4;

  cast_gate_kernel<<<4096, 256, 0, stream>>>(hs, hsb, gru_w, gru_b, gconst, gatep);
  cast_w_kernel<<<dim3(1024, 5), 256, 0, stream>>>(q_w, k_w, v_w, out_w, wcat, wob, rel, pbt);

  const float qalpha = 0.125f * LOG2E;
  gemm2_kernel<1, 3072><<<dim3(24, 32), 256, 0, stream>>>(
      hsb, wcat, q_b, k_b, v_b, qalpha, Qb, Kb, Vtb);

  attn3_kernel<<<512, 512, 0, stream>>>(Qb, Kb, Vtb, gatep, pbt, ctxb);

  gemm_o_kernel<<<dim3(8, 64), 256, 0, stream>>>(ctxb, wob, out_b, (float*)d_out);
}

// Round 16
// 214.633 us; speedup vs baseline: 1.0844x; 1.0068x over previous
//
#include <hip/hip_runtime.h>
#include <hip/hip_bf16.h>
#include <math.h>

typedef __bf16 bf16;
typedef __bf16 bf16x4 __attribute__((ext_vector_type(4)));
typedef __bf16 bf16x8 __attribute__((ext_vector_type(8)));
typedef float  f32x4  __attribute__((ext_vector_type(4)));
typedef unsigned u32x2 __attribute__((ext_vector_type(2)));
typedef unsigned u32x4 __attribute__((ext_vector_type(4)));

#define T_SEQ 2048
#define E_DIM 1024
#define H_NUM 16
#define D_DIM 64
#define NDELTA 4095
#define LOG2E 1.4426950408889634f

__device__ __forceinline__ void gld16(const bf16* g, bf16* l) {
  __builtin_amdgcn_global_load_lds((__attribute__((address_space(1))) void*)(g),
                                   (__attribute__((address_space(3))) void*)(l), 16, 0, 0);
}

// in-register qd-group exchange via official gfx950 builtins
__device__ __forceinline__ void qswap(unsigned &a, unsigned &b) {
  u32x2 t  = __builtin_amdgcn_permlane32_swap(a, b, false, false);
  u32x2 t2 = __builtin_amdgcn_permlane16_swap(t[0], t[1], false, false);
  a = t2[0]; b = t2[1];
}

// ---------------- fused fp32->bf16 cast + gate (one block per bt row) ----------------
__global__ __launch_bounds__(256)
void cast_gate_kernel(const float* __restrict__ hs, bf16* __restrict__ hsb,
                      const float* __restrict__ gru_w, const float* __restrict__ gru_b,
                      const float* __restrict__ gconst, float* __restrict__ gate)
{
  __shared__ float w[512];
  const int tid = threadIdx.x;
  const int bt  = blockIdx.x;
  w[tid]       = gru_w[tid];
  w[tid + 256] = gru_w[tid + 256];
  __syncthreads();

  const int i = bt * 256 + tid;
  const float4 xv = reinterpret_cast<const float4*>(hs)[i];
  bf16x4 o;
  o[0] = (bf16)xv.x; o[1] = (bf16)xv.y; o[2] = (bf16)xv.z; o[3] = (bf16)xv.w;
  reinterpret_cast<bf16x4*>(hsb)[i] = o;

  const int h  = tid >> 4;
  const int d0 = (tid & 15) * 4;
  float acc[8];
#pragma unroll
  for (int e = 0; e < 8; e++) {
    acc[e] = xv.x * w[e*64+d0] + xv.y * w[e*64+d0+1]
           + xv.z * w[e*64+d0+2] + xv.w * w[e*64+d0+3];
  }
#pragma unroll
  for (int e = 0; e < 8; e++) {
    float v = acc[e];
    v += __shfl_xor(v, 1);
    v += __shfl_xor(v, 2);
    v += __shfl_xor(v, 4);
    v += __shfl_xor(v, 8);
    acc[e] = v;
  }
  if ((tid & 15) == 0) {
    float p0 = acc[0]+acc[1]+acc[2]+acc[3] + gru_b[0]+gru_b[1]+gru_b[2]+gru_b[3];
    float p1 = acc[4]+acc[5]+acc[6]+acc[7] + gru_b[4]+gru_b[5]+gru_b[6]+gru_b[7];
    float ga = 1.0f / (1.0f + expf(-p0));
    float gb = 1.0f / (1.0f + expf(-p1));
    float g = (ga * (gb * gconst[h] - 1.0f) + 2.0f) * LOG2E;
    int bb = bt >> 11;
    int t  = bt & (T_SEQ - 1);
    gate[((size_t)(bb * H_NUM + h)) * T_SEQ + t] = g;
  }
}

// ---------------- weight casts (y=0..3) + position-bias table (y=4) ----------------
__global__ void cast_w_kernel(const float* __restrict__ q_w, const float* __restrict__ k_w,
                              const float* __restrict__ v_w, const float* __restrict__ o_w,
                              bf16* __restrict__ wcat, bf16* __restrict__ wob,
                              const float* __restrict__ rel_embed, float* __restrict__ pbt) {
  int sel = blockIdx.y;
  int tid = threadIdx.x;
  if (sel == 4) {
    int dd = blockIdx.x * 256 + tid;
    if (blockIdx.x >= 16 || dd >= NDELTA) return;
    int delta = dd - (T_SEQ - 1);
    int bucket = (delta > 0) ? 160 : 0;
    int rel = abs(delta);
    int v;
    if (rel < 80) {
      v = rel;
    } else {
      float rf = (float)(rel < 1 ? 1 : rel);
      float lf = logf(rf / 80.0f) * (80.0f / 2.302585092994046f);
      int lg = 80 + (int)lf;
      v = lg < 159 ? lg : 159;
    }
    bucket += v;
#pragma unroll
    for (int h = 0; h < H_NUM; h++)
      pbt[h * NDELTA + dd] = rel_embed[bucket * H_NUM + h];
    return;
  }
  int i = blockIdx.x * 256 + tid;
  const float* src = (sel == 0) ? q_w : (sel == 1) ? k_w : (sel == 2) ? v_w : o_w;
  bf16* dst = (sel < 3) ? (wcat + (size_t)sel * 1048576) : wob;
  const float4 v = reinterpret_cast<const float4*>(src)[i];
  bf16x4 o;
  o[0] = (bf16)v.x; o[1] = (bf16)v.y; o[2] = (bf16)v.z; o[3] = (bf16)v.w;
  reinterpret_cast<bf16x4*>(dst)[i] = o;
}

// ---------------- GEMM v3: BK=64 + XOR chunk swizzle + XCD-rectangle remap ----------------
// Grid is flat 768 = 8 XCDs x (12 n-blocks x 8 m-blocks). All blocks with
// wid&7 == p land on XCD p (proven by r15's attn FETCH 70.6->12.7 MB), so each
// XCD L2 holds a 12x8 rectangle's working set (3 MB W + 2 MB A) instead of
// round-robin fetching every panel (up to 8x duplication).
template<int MODE, int N_TOTAL>
__global__ __launch_bounds__(256)
void gemm2_kernel(const bf16* __restrict__ A, const bf16* __restrict__ W,
                  const float* __restrict__ b0, const float* __restrict__ b1,
                  const float* __restrict__ b2, float qalpha,
                  void* __restrict__ out0, void* __restrict__ out1, void* __restrict__ out2)
{
  __shared__ bf16 As[128 * 64];
  __shared__ bf16 Bs[128 * 64];
  const int tid  = threadIdx.x;
  const int lane = tid & 63;
  const int wave = tid >> 6;
  // XCD-rectangle remap: xcd p covers n-blocks [(p&1)*12, +12), m-blocks [(p>>1)*8, +8)
  const int wid0  = blockIdx.x;          // 0..767
  const int xcd   = wid0 & 7;
  const int local = wid0 >> 3;           // 0..95
  const int nb_   = (xcd & 1) * 12 + (local % 12);
  const int mb_   = (xcd >> 1) * 8 + (local / 12);
  const int m0 = mb_ * 128;
  const int n0 = nb_ * 128;
  const int wm = (wave >> 1) * 64;
  const int wn = (wave & 1) * 64;
  const int qd = lane >> 4;
  const int lm = lane & 15;

  const int srow8  = lane >> 3;
  const int schunk = ((lane & 7) ^ srow8) * 8;
  const bf16* gA = A + (size_t)(m0 + wave * 32 + srow8) * 1024 + schunk;
  const bf16* gB = W + (size_t)(n0 + wave * 32 + srow8) * 1024 + schunk;
  bf16* lA = As + wave * 32 * 64;
  bf16* lB = Bs + wave * 32 * 64;

  f32x4 acc[4][4] = {};
  const int xs = lm & 7;

  for (int k0 = 0; k0 < 1024; k0 += 64) {
#pragma unroll
    for (int j = 0; j < 4; j++) {
      gld16(gA + (size_t)j * 8 * 1024 + k0, lA + j * 8 * 64);
      gld16(gB + (size_t)j * 8 * 1024 + k0, lB + j * 8 * 64);
    }
    __syncthreads();
    bf16x8 af[4][2], bfr[4][2];
#pragma unroll
    for (int i = 0; i < 4; i++) {
#pragma unroll
      for (int kk = 0; kk < 2; kk++) {
        af[i][kk]  = *(const bf16x8*)&As[(wm + i * 16 + lm) * 64 + (((kk * 4 + qd) ^ xs) * 8)];
        bfr[i][kk] = *(const bf16x8*)&Bs[(wn + i * 16 + lm) * 64 + (((kk * 4 + qd) ^ xs) * 8)];
      }
    }
#pragma unroll
    for (int kk = 0; kk < 2; kk++)
#pragma unroll
      for (int im = 0; im < 4; im++)
#pragma unroll
        for (int in = 0; in < 4; in++)
          acc[im][in] = __builtin_amdgcn_mfma_f32_16x16x32_bf16(af[im][kk], bfr[in][kk], acc[im][in], 0, 0, 0);
    __syncthreads();
  }

  const int seg = n0 >> 10;
  const float* bias = (MODE == 0) ? b0 : (seg == 0 ? b0 : (seg == 1 ? b1 : b2));
  const float alpha = (MODE == 1 && seg == 0) ? qalpha : 1.0f;

#pragma unroll
  for (int im = 0; im < 4; im++) {
#pragma unroll
    for (int in = 0; in < 4; in++) {
      const int n  = n0 + wn + in * 16 + lm;
      const int n1 = n & 1023;
      const float bv = bias[n1];
      const int mb = m0 + wm + im * 16 + qd * 4;
      if (MODE == 0) {
        float* o = (float*)out0;
#pragma unroll
        for (int r = 0; r < 4; r++)
          o[(size_t)(mb + r) * 1024 + n1] = acc[im][in][r] + bv;
      } else if (seg == 2) {
        const int bb = mb >> 11;
        const int t  = mb & 2047;
        bf16x4 pk;
#pragma unroll
        for (int r = 0; r < 4; r++) pk[r] = (bf16)(acc[im][in][r] + bv);
        *(bf16x4*)&((bf16*)out2)[((size_t)(bb * 1024 + n1)) * 2048 + t] = pk;
      } else {
        bf16* o = (bf16*)(seg == 0 ? out0 : out1);
#pragma unroll
        for (int r = 0; r < 4; r++)
          o[(size_t)(mb + r) * 1024 + n1] = (bf16)((acc[im][in][r] + bv) * alpha);
      }
    }
  }
}

// ---------------- O-projection GEMM: 64x128 tile + XCD-rectangle remap ----------------
// Flat 512 = 8 XCDs x (8 n-blocks x 8 m-blocks): per-XCD 2 MB W + 1 MB A.
__global__ __launch_bounds__(256)
void gemm_o_kernel(const bf16* __restrict__ A, const bf16* __restrict__ W,
                   const float* __restrict__ bias, float* __restrict__ out)
{
  __shared__ bf16 As[64 * 32];
  __shared__ bf16 Bs[128 * 32];
  const int tid  = threadIdx.x;
  const int lane = tid & 63;
  const int wave = tid >> 6;
  const int wid0  = blockIdx.x;          // 0..511
  const int xcd   = wid0 & 7;
  const int local = wid0 >> 3;           // 0..63
  const int n0 = (local & 7) * 128;
  const int m0 = (xcd * 8 + (local >> 3)) * 64;
  const int wm = (wave >> 1) * 32;
  const int wn = (wave & 1) * 64;
  const int qd = lane >> 4;
  const int lm = lane & 15;

  const int row4 = lane >> 2;
  const int col8 = (lane & 3) * 8;
  const bf16* gA0 = A + (size_t)(m0 + wave * 16 + row4) * 1024 + col8;
  const bf16* gB0 = W + (size_t)(n0 + wave * 32 + row4) * 1024 + col8;
  const bf16* gB1 = gB0 + (size_t)16 * 1024;
  bf16* lA0 = As + wave * 16 * 32;
  bf16* lB0 = Bs + (wave * 2 + 0) * 512;
  bf16* lB1 = Bs + (wave * 2 + 1) * 512;

  f32x4 acc[2][4] = {};

  for (int k0 = 0; k0 < 1024; k0 += 32) {
    gld16(gA0 + k0, lA0);
    gld16(gB0 + k0, lB0);
    gld16(gB1 + k0, lB1);
    __syncthreads();
    bf16x8 af[2], bfr[4];
#pragma unroll
    for (int i = 0; i < 2; i++)
      af[i]  = *(const bf16x8*)&As[(wm + i * 16 + lm) * 32 + qd * 8];
#pragma unroll
    for (int i = 0; i < 4; i++)
      bfr[i] = *(const bf16x8*)&Bs[(wn + i * 16 + lm) * 32 + qd * 8];
#pragma unroll
    for (int im = 0; im < 2; im++)
#pragma unroll
      for (int in = 0; in < 4; in++)
        acc[im][in] = __builtin_amdgcn_mfma_f32_16x16x32_bf16(af[im], bfr[in], acc[im][in], 0, 0, 0);
    __syncthreads();
  }

#pragma unroll
  for (int im = 0; im < 2; im++) {
#pragma unroll
    for (int in = 0; in < 4; in++) {
      const int n  = n0 + wn + in * 16 + lm;
      const float bv = bias[n];
      const int mb = m0 + wm + im * 16 + qd * 4;
#pragma unroll
      for (int r = 0; r < 4; r++)
        out[(size_t)(mb + r) * 1024 + n] = acc[im][in][r] + bv;
    }
  }
}

// ---------------- flash attention v7 + XCD-chunked block swizzle (round-15, best) ----------------
#define LK 72
__global__ __launch_bounds__(512)
void attn3_kernel(const bf16* __restrict__ Qg, const bf16* __restrict__ Kg,
                  const bf16* __restrict__ Vtg, const float* __restrict__ gate,
                  const float* __restrict__ pbt, bf16* __restrict__ ctx)
{
  __shared__ bf16 Ks[2][64 * LK];
  __shared__ bf16 Vs[2][64 * LK];
  __shared__ float pbs[2176];

  const int wid0 = blockIdx.x;                       // 0..511 (hw linear)
  const int wid  = ((wid0 & 7) << 6) | (wid0 >> 3);  // XCD-chunked remap
  const int t0 = (wid & 15) * 128;
  const int h  = (wid >> 4) & 15;
  const int b  = wid >> 8;
  const int tid  = threadIdx.x;
  const int lane = tid & 63;
  const int wave = tid >> 6;        // 0..7
  const int qd = lane >> 4;
  const int lm = lane & 15;

  for (int i = tid; i < 2176; i += 512) {
    int idx = i - t0 + 1920;
    pbs[i] = (idx >= 0 && idx < NDELTA) ? pbt[h * NDELTA + idx] : 0.0f;
  }

  // each wave owns 16 q-rows: q = t0 + wave*16 + lm
  const int rowoff = wave * 16 + lm;
  bf16x8 qf[2];
  float g;
  {
    const int q = t0 + rowoff;
    const bf16* qrow = Qg + (size_t)(b * T_SEQ + q) * E_DIM + h * D_DIM;
    qf[0] = *(const bf16x8*)(qrow + qd * 8);
    qf[1] = *(const bf16x8*)(qrow + 32 + qd * 8);
    g = gate[((size_t)(b * H_NUM + h)) * T_SEQ + q];
  }

  // staging: 512 threads, each 1 bf16x8 chunk of K and of V (64 rows x 64 cols)
  const int srow = tid >> 3;
  const int scol = (tid & 7) * 8;
  const bf16* kgp = Kg  + ((size_t)(b * T_SEQ) + srow) * E_DIM + h * D_DIM + scol;
  const bf16* vgp = Vtg + ((size_t)(b * 1024) + h * D_DIM + srow) * T_SEQ + scol;

  {
    bf16x8 a0 = *(const bf16x8*)kgp;
    bf16x8 c0 = *(const bf16x8*)vgp;
    *(bf16x8*)&Ks[0][srow * LK + scol] = a0;
    *(bf16x8*)&Vs[0][srow * LK + scol] = c0;
  }
  __syncthreads();

  f32x4 o[4] = {};
  float li = 0.0f;

  for (int it = 0; it < T_SEQ / 64; it++) {
    const int s0 = it * 64;
    const int buf = it & 1;
    const bool more = (it + 1 < T_SEQ / 64);
    bf16x8 nk0, nv0;
    if (more) {
      nk0 = *(const bf16x8*)(kgp + (size_t)(s0 + 64) * E_DIM);
      nv0 = *(const bf16x8*)(vgp + (s0 + 64));
    }

    bf16x8 kf[4][2];
#pragma unroll
    for (int mb = 0; mb < 4; mb++) {
      kf[mb][0] = *(const bf16x8*)&Ks[buf][(16 * mb + lm) * LK + qd * 8];
      kf[mb][1] = *(const bf16x8*)&Ks[buf][(16 * mb + lm) * LK + 32 + qd * 8];
    }

    f32x4 sc[4];
#pragma unroll
    for (int mb = 0; mb < 4; mb++) {
      f32x4 t = {};
      t = __builtin_amdgcn_mfma_f32_16x16x32_bf16(kf[mb][0], qf[0], t, 0, 0, 0);
      t = __builtin_amdgcn_mfma_f32_16x16x32_bf16(kf[mb][1], qf[1], t, 0, 0, 0);
      sc[mb] = t;
    }
    const int ib = s0 + 4 * qd + 127 - rowoff;
    float rs = 0.0f;
    unsigned wlo[4], whi[4];
#pragma unroll
    for (int mb = 0; mb < 4; mb++) {
      bf16x4 pk;
#pragma unroll
      for (int r = 0; r < 4; r++) {
        float p = __builtin_amdgcn_exp2f(sc[mb][r] + g * pbs[ib + 16 * mb + r]);
        rs += p;
        pk[r] = (bf16)p;
      }
      u32x2 pw = __builtin_bit_cast(u32x2, pk);
      wlo[mb] = pw[0]; whi[mb] = pw[1];
    }
    li += rs;
    bf16x8 pf[2];
    {
      unsigned a0 = wlo[0], b0v = wlo[1], a1 = whi[0], b1v = whi[1];
      qswap(a0, b0v);
      qswap(a1, b1v);
      u32x4 h0; h0[0] = a0; h0[1] = a1; h0[2] = b0v; h0[3] = b1v;
      pf[0] = __builtin_bit_cast(bf16x8, h0);
      unsigned c0 = wlo[2], d0v = wlo[3], c1 = whi[2], d1v = whi[3];
      qswap(c0, d0v);
      qswap(c1, d1v);
      u32x4 h1; h1[0] = c0; h1[1] = c1; h1[2] = d0v; h1[3] = d1v;
      pf[1] = __builtin_bit_cast(bf16x8, h1);
    }

#pragma unroll
    for (int db = 0; db < 4; db++) {
      bf16x8 vf0 = *(const bf16x8*)&Vs[buf][(16 * db + lm) * LK + qd * 8];
      bf16x8 vf1 = *(const bf16x8*)&Vs[buf][(16 * db + lm) * LK + 32 + qd * 8];
      o[db] = __builtin_amdgcn_mfma_f32_16x16x32_bf16(vf0, pf[0], o[db], 0, 0, 0);
      o[db] = __builtin_amdgcn_mfma_f32_16x16x32_bf16(vf1, pf[1], o[db], 0, 0, 0);
    }
    if (more) {
      *(bf16x8*)&Ks[buf ^ 1][srow * LK + scol] = nk0;
      *(bf16x8*)&Vs[buf ^ 1][srow * LK + scol] = nv0;
    }
    __syncthreads();
  }

  li += __shfl_xor(li, 16);
  li += __shfl_xor(li, 32);
  {
    const float inv = 1.0f / li;
    const int q = t0 + rowoff;
    bf16* obase = ctx + (size_t)(b * T_SEQ + q) * E_DIM + h * D_DIM + 4 * qd;
#pragma unroll
    for (int db = 0; db < 4; db++) {
      bf16x4 ov;
      ov[0] = (bf16)(o[db][0] * inv); ov[1] = (bf16)(o[db][1] * inv);
      ov[2] = (bf16)(o[db][2] * inv); ov[3] = (bf16)(o[db][3] * inv);
      *(bf16x4*)&obase[16 * db] = ov;
    }
  }
}

// ---------------- orchestration ----------------
extern "C" void kernel_launch(void* const* d_in, const int* in_sizes, int n_in,
                              void* d_out, int out_size, void* d_ws, size_t ws_size,
                              hipStream_t stream)
{
  const float* hs     = (const float*)d_in[0];
  const float* q_w    = (const float*)d_in[1];
  const float* q_b    = (const float*)d_in[2];
  const float* k_w    = (const float*)d_in[3];
  const float* k_b    = (const float*)d_in[4];
  const float* v_w    = (const float*)d_in[5];
  const float* v_b    = (const float*)d_in[6];
  const float* out_w  = (const float*)d_in[7];
  const float* out_b  = (const float*)d_in[8];
  const float* rel    = (const float*)d_in[9];
  const float* gconst = (const float*)d_in[10];
  const float* gru_w  = (const float*)d_in[11];
  const float* gru_b  = (const float*)d_in[12];

  char* p = (char*)d_ws;
  bf16* hsb  = (bf16*)p; p += (size_t)4096 * 1024 * 2;
  bf16* wcat = (bf16*)p; p += (size_t)3072 * 1024 * 2;
  bf16* wob  = (bf16*)p; p += (size_t)1024 * 1024 * 2;
  bf16* Qb   = (bf16*)p; p += (size_t)4096 * 1024 * 2;
  bf16* Kb   = (bf16*)p; p += (size_t)4096 * 1024 * 2;
  bf16* Vtb  = (bf16*)p; p += (size_t)2048 * 2048 * 2;
  bf16* ctxb = (bf16*)p; p += (size_t)4096 * 1024 * 2;
  float* gatep = (float*)p; p += (size_t)2 * H_NUM * T_SEQ * 4;
  float* pbt   = (float*)p; p += (size_t)H_NUM * NDELTA * 4;

  cast_gate_kernel<<<4096, 256, 0, stream>>>(hs, hsb, gru_w, gru_b, gconst, gatep);
  cast_w_kernel<<<dim3(1024, 5), 256, 0, stream>>>(q_w, k_w, v_w, out_w, wcat, wob, rel, pbt);

  const float qalpha = 0.125f * LOG2E;
  gemm2_kernel<1, 3072><<<768, 256, 0, stream>>>(
      hsb, wcat, q_b, k_b, v_b, qalpha, Qb, Kb, Vtb);

  attn3_kernel<<<512, 512, 0, stream>>>(Qb, Kb, Vtb, gatep, pbt, ctxb);

  gemm_o_kernel<<<512, 256, 0, stream>>>(ctxb, wob, out_b, (float*)d_out);
}

// Round 17
// 212.448 us; speedup vs baseline: 1.0956x; 1.0103x over previous
//
#include <hip/hip_runtime.h>
#include <hip/hip_bf16.h>
#include <math.h>

typedef __bf16 bf16;
typedef __bf16 bf16x4 __attribute__((ext_vector_type(4)));
typedef __bf16 bf16x8 __attribute__((ext_vector_type(8)));
typedef float  f32x4  __attribute__((ext_vector_type(4)));
typedef unsigned u32x2 __attribute__((ext_vector_type(2)));
typedef unsigned u32x4 __attribute__((ext_vector_type(4)));

#define T_SEQ 2048
#define E_DIM 1024
#define H_NUM 16
#define D_DIM 64
#define NDELTA 4095
#define LOG2E 1.4426950408889634f

__device__ __forceinline__ void gld16(const bf16* g, bf16* l) {
  __builtin_amdgcn_global_load_lds((__attribute__((address_space(1))) void*)(g),
                                   (__attribute__((address_space(3))) void*)(l), 16, 0, 0);
}

// in-register qd-group exchange via official gfx950 builtins
__device__ __forceinline__ void qswap(unsigned &a, unsigned &b) {
  u32x2 t  = __builtin_amdgcn_permlane32_swap(a, b, false, false);
  u32x2 t2 = __builtin_amdgcn_permlane16_swap(t[0], t[1], false, false);
  a = t2[0]; b = t2[1];
}

// ---------------- fused prep: hs-cast+gate | weight casts | pb table ----------------
// One launch replaces cast_gate (4096 blocks) + cast_w (4096+pb blocks): removes a
// launch gap and lets the two independent memory-bound streams share HBM BW.
// Block-uniform branching; barrier only in the gate branch (all its threads reach it).
__global__ __launch_bounds__(256)
void prep_kernel(const float* __restrict__ hs, bf16* __restrict__ hsb,
                 const float* __restrict__ gru_w, const float* __restrict__ gru_b,
                 const float* __restrict__ gconst, float* __restrict__ gate,
                 const float* __restrict__ q_w, const float* __restrict__ k_w,
                 const float* __restrict__ v_w, const float* __restrict__ o_w,
                 bf16* __restrict__ wcat, bf16* __restrict__ wob,
                 const float* __restrict__ rel_embed, float* __restrict__ pbt)
{
  __shared__ float w[512];
  const int bid = blockIdx.x;
  const int tid = threadIdx.x;

  if (bid < 4096) {
    // ---- hs cast + gate (one block per bt row) ----
    const int bt = bid;
    w[tid]       = gru_w[tid];
    w[tid + 256] = gru_w[tid + 256];
    __syncthreads();

    const int i = bt * 256 + tid;
    const float4 xv = reinterpret_cast<const float4*>(hs)[i];
    bf16x4 o;
    o[0] = (bf16)xv.x; o[1] = (bf16)xv.y; o[2] = (bf16)xv.z; o[3] = (bf16)xv.w;
    reinterpret_cast<bf16x4*>(hsb)[i] = o;

    const int h  = tid >> 4;
    const int d0 = (tid & 15) * 4;
    float acc[8];
#pragma unroll
    for (int e = 0; e < 8; e++) {
      acc[e] = xv.x * w[e*64+d0] + xv.y * w[e*64+d0+1]
             + xv.z * w[e*64+d0+2] + xv.w * w[e*64+d0+3];
    }
#pragma unroll
    for (int e = 0; e < 8; e++) {
      float v = acc[e];
      v += __shfl_xor(v, 1);
      v += __shfl_xor(v, 2);
      v += __shfl_xor(v, 4);
      v += __shfl_xor(v, 8);
      acc[e] = v;
    }
    if ((tid & 15) == 0) {
      float p0 = acc[0]+acc[1]+acc[2]+acc[3] + gru_b[0]+gru_b[1]+gru_b[2]+gru_b[3];
      float p1 = acc[4]+acc[5]+acc[6]+acc[7] + gru_b[4]+gru_b[5]+gru_b[6]+gru_b[7];
      float ga = 1.0f / (1.0f + expf(-p0));
      float gb = 1.0f / (1.0f + expf(-p1));
      float g = (ga * (gb * gconst[h] - 1.0f) + 2.0f) * LOG2E;
      int bb = bt >> 11;
      int t  = bt & (T_SEQ - 1);
      gate[((size_t)(bb * H_NUM + h)) * T_SEQ + t] = g;
    }
  } else if (bid < 8192) {
    // ---- weight casts: sel 0..3 over q/k/v/o ----
    const int wb  = bid - 4096;
    const int sel = wb >> 10;
    const int i   = (wb & 1023) * 256 + tid;
    const float* src = (sel == 0) ? q_w : (sel == 1) ? k_w : (sel == 2) ? v_w : o_w;
    bf16* dst = (sel < 3) ? (wcat + (size_t)sel * 1048576) : wob;
    const float4 v = reinterpret_cast<const float4*>(src)[i];
    bf16x4 o;
    o[0] = (bf16)v.x; o[1] = (bf16)v.y; o[2] = (bf16)v.z; o[3] = (bf16)v.w;
    reinterpret_cast<bf16x4*>(dst)[i] = o;
  } else {
    // ---- position-bias table (16 blocks) ----
    const int dd = (bid - 8192) * 256 + tid;
    if (dd >= NDELTA) return;
    int delta = dd - (T_SEQ - 1);
    int bucket = (delta > 0) ? 160 : 0;
    int rel = abs(delta);
    int v;
    if (rel < 80) {
      v = rel;
    } else {
      float rf = (float)(rel < 1 ? 1 : rel);
      float lf = logf(rf / 80.0f) * (80.0f / 2.302585092994046f);
      int lg = 80 + (int)lf;
      v = lg < 159 ? lg : 159;
    }
    bucket += v;
#pragma unroll
    for (int h = 0; h < H_NUM; h++)
      pbt[h * NDELTA + dd] = rel_embed[bucket * H_NUM + h];
  }
}

// ---------------- GEMM v3: BK=64 + XOR chunk swizzle + XCD-rectangle remap ----------------
template<int MODE, int N_TOTAL>
__global__ __launch_bounds__(256)
void gemm2_kernel(const bf16* __restrict__ A, const bf16* __restrict__ W,
                  const float* __restrict__ b0, const float* __restrict__ b1,
                  const float* __restrict__ b2, float qalpha,
                  void* __restrict__ out0, void* __restrict__ out1, void* __restrict__ out2)
{
  __shared__ bf16 As[128 * 64];
  __shared__ bf16 Bs[128 * 64];
  const int tid  = threadIdx.x;
  const int lane = tid & 63;
  const int wave = tid >> 6;
  // XCD-rectangle remap: xcd p covers n-blocks [(p&1)*12, +12), m-blocks [(p>>1)*8, +8)
  const int wid0  = blockIdx.x;          // 0..767
  const int xcd   = wid0 & 7;
  const int local = wid0 >> 3;           // 0..95
  const int nb_   = (xcd & 1) * 12 + (local % 12);
  const int mb_   = (xcd >> 1) * 8 + (local / 12);
  const int m0 = mb_ * 128;
  const int n0 = nb_ * 128;
  const int wm = (wave >> 1) * 64;
  const int wn = (wave & 1) * 64;
  const int qd = lane >> 4;
  const int lm = lane & 15;

  const int srow8  = lane >> 3;
  const int schunk = ((lane & 7) ^ srow8) * 8;
  const bf16* gA = A + (size_t)(m0 + wave * 32 + srow8) * 1024 + schunk;
  const bf16* gB = W + (size_t)(n0 + wave * 32 + srow8) * 1024 + schunk;
  bf16* lA = As + wave * 32 * 64;
  bf16* lB = Bs + wave * 32 * 64;

  f32x4 acc[4][4] = {};
  const int xs = lm & 7;

  for (int k0 = 0; k0 < 1024; k0 += 64) {
#pragma unroll
    for (int j = 0; j < 4; j++) {
      gld16(gA + (size_t)j * 8 * 1024 + k0, lA + j * 8 * 64);
      gld16(gB + (size_t)j * 8 * 1024 + k0, lB + j * 8 * 64);
    }
    __syncthreads();
    bf16x8 af[4][2], bfr[4][2];
#pragma unroll
    for (int i = 0; i < 4; i++) {
#pragma unroll
      for (int kk = 0; kk < 2; kk++) {
        af[i][kk]  = *(const bf16x8*)&As[(wm + i * 16 + lm) * 64 + (((kk * 4 + qd) ^ xs) * 8)];
        bfr[i][kk] = *(const bf16x8*)&Bs[(wn + i * 16 + lm) * 64 + (((kk * 4 + qd) ^ xs) * 8)];
      }
    }
#pragma unroll
    for (int kk = 0; kk < 2; kk++)
#pragma unroll
      for (int im = 0; im < 4; im++)
#pragma unroll
        for (int in = 0; in < 4; in++)
          acc[im][in] = __builtin_amdgcn_mfma_f32_16x16x32_bf16(af[im][kk], bfr[in][kk], acc[im][in], 0, 0, 0);
    __syncthreads();
  }

  const int seg = n0 >> 10;
  const float* bias = (MODE == 0) ? b0 : (seg == 0 ? b0 : (seg == 1 ? b1 : b2));
  const float alpha = (MODE == 1 && seg == 0) ? qalpha : 1.0f;

#pragma unroll
  for (int im = 0; im < 4; im++) {
#pragma unroll
    for (int in = 0; in < 4; in++) {
      const int n  = n0 + wn + in * 16 + lm;
      const int n1 = n & 1023;
      const float bv = bias[n1];
      const int mb = m0 + wm + im * 16 + qd * 4;
      if (MODE == 0) {
        float* o = (float*)out0;
#pragma unroll
        for (int r = 0; r < 4; r++)
          o[(size_t)(mb + r) * 1024 + n1] = acc[im][in][r] + bv;
      } else if (seg == 2) {
        const int bb = mb >> 11;
        const int t  = mb & 2047;
        bf16x4 pk;
#pragma unroll
        for (int r = 0; r < 4; r++) pk[r] = (bf16)(acc[im][in][r] + bv);
        *(bf16x4*)&((bf16*)out2)[((size_t)(bb * 1024 + n1)) * 2048 + t] = pk;
      } else {
        bf16* o = (bf16*)(seg == 0 ? out0 : out1);
#pragma unroll
        for (int r = 0; r < 4; r++)
          o[(size_t)(mb + r) * 1024 + n1] = (bf16)((acc[im][in][r] + bv) * alpha);
      }
    }
  }
}

// ---------------- O-projection GEMM: 64x128 tile + XCD-rectangle remap ----------------
__global__ __launch_bounds__(256)
void gemm_o_kernel(const bf16* __restrict__ A, const bf16* __restrict__ W,
                   const float* __restrict__ bias, float* __restrict__ out)
{
  __shared__ bf16 As[64 * 32];
  __shared__ bf16 Bs[128 * 32];
  const int tid  = threadIdx.x;
  const int lane = tid & 63;
  const int wave = tid >> 6;
  const int wid0  = blockIdx.x;          // 0..511
  const int xcd   = wid0 & 7;
  const int local = wid0 >> 3;           // 0..63
  const int n0 = (local & 7) * 128;
  const int m0 = (xcd * 8 + (local >> 3)) * 64;
  const int wm = (wave >> 1) * 32;
  const int wn = (wave & 1) * 64;
  const int qd = lane >> 4;
  const int lm = lane & 15;

  const int row4 = lane >> 2;
  const int col8 = (lane & 3) * 8;
  const bf16* gA0 = A + (size_t)(m0 + wave * 16 + row4) * 1024 + col8;
  const bf16* gB0 = W + (size_t)(n0 + wave * 32 + row4) * 1024 + col8;
  const bf16* gB1 = gB0 + (size_t)16 * 1024;
  bf16* lA0 = As + wave * 16 * 32;
  bf16* lB0 = Bs + (wave * 2 + 0) * 512;
  bf16* lB1 = Bs + (wave * 2 + 1) * 512;

  f32x4 acc[2][4] = {};

  for (int k0 = 0; k0 < 1024; k0 += 32) {
    gld16(gA0 + k0, lA0);
    gld16(gB0 + k0, lB0);
    gld16(gB1 + k0, lB1);
    __syncthreads();
    bf16x8 af[2], bfr[4];
#pragma unroll
    for (int i = 0; i < 2; i++)
      af[i]  = *(const bf16x8*)&As[(wm + i * 16 + lm) * 32 + qd * 8];
#pragma unroll
    for (int i = 0; i < 4; i++)
      bfr[i] = *(const bf16x8*)&Bs[(wn + i * 16 + lm) * 32 + qd * 8];
#pragma unroll
    for (int im = 0; im < 2; im++)
#pragma unroll
      for (int in = 0; in < 4; in++)
        acc[im][in] = __builtin_amdgcn_mfma_f32_16x16x32_bf16(af[im], bfr[in], acc[im][in], 0, 0, 0);
    __syncthreads();
  }

#pragma unroll
  for (int im = 0; im < 2; im++) {
#pragma unroll
    for (int in = 0; in < 4; in++) {
      const int n  = n0 + wn + in * 16 + lm;
      const float bv = bias[n];
      const int mb = m0 + wm + im * 16 + qd * 4;
#pragma unroll
      for (int r = 0; r < 4; r++)
        out[(size_t)(mb + r) * 1024 + n] = acc[im][in][r] + bv;
    }
  }
}

// ---------------- flash attention v7 + XCD-chunked block swizzle (best: 61.6 us) ----------------
#define LK 72
__global__ __launch_bounds__(512)
void attn3_kernel(const bf16* __restrict__ Qg, const bf16* __restrict__ Kg,
                  const bf16* __restrict__ Vtg, const float* __restrict__ gate,
                  const float* __restrict__ pbt, bf16* __restrict__ ctx)
{
  __shared__ bf16 Ks[2][64 * LK];
  __shared__ bf16 Vs[2][64 * LK];
  __shared__ float pbs[2176];

  const int wid0 = blockIdx.x;                       // 0..511 (hw linear)
  const int wid  = ((wid0 & 7) << 6) | (wid0 >> 3);  // XCD-chunked remap
  const int t0 = (wid & 15) * 128;
  const int h  = (wid >> 4) & 15;
  const int b  = wid >> 8;
  const int tid  = threadIdx.x;
  const int lane = tid & 63;
  const int wave = tid >> 6;        // 0..7
  const int qd = lane >> 4;
  const int lm = lane & 15;

  for (int i = tid; i < 2176; i += 512) {
    int idx = i - t0 + 1920;
    pbs[i] = (idx >= 0 && idx < NDELTA) ? pbt[h * NDELTA + idx] : 0.0f;
  }

  const int rowoff = wave * 16 + lm;
  bf16x8 qf[2];
  float g;
  {
    const int q = t0 + rowoff;
    const bf16* qrow = Qg + (size_t)(b * T_SEQ + q) * E_DIM + h * D_DIM;
    qf[0] = *(const bf16x8*)(qrow + qd * 8);
    qf[1] = *(const bf16x8*)(qrow + 32 + qd * 8);
    g = gate[((size_t)(b * H_NUM + h)) * T_SEQ + q];
  }

  const int srow = tid >> 3;
  const int scol = (tid & 7) * 8;
  const bf16* kgp = Kg  + ((size_t)(b * T_SEQ) + srow) * E_DIM + h * D_DIM + scol;
  const bf16* vgp = Vtg + ((size_t)(b * 1024) + h * D_DIM + srow) * T_SEQ + scol;

  {
    bf16x8 a0 = *(const bf16x8*)kgp;
    bf16x8 c0 = *(const bf16x8*)vgp;
    *(bf16x8*)&Ks[0][srow * LK + scol] = a0;
    *(bf16x8*)&Vs[0][srow * LK + scol] = c0;
  }
  __syncthreads();

  f32x4 o[4] = {};
  float li = 0.0f;

  for (int it = 0; it < T_SEQ / 64; it++) {
    const int s0 = it * 64;
    const int buf = it & 1;
    const bool more = (it + 1 < T_SEQ / 64);
    bf16x8 nk0, nv0;
    if (more) {
      nk0 = *(const bf16x8*)(kgp + (size_t)(s0 + 64) * E_DIM);
      nv0 = *(const bf16x8*)(vgp + (s0 + 64));
    }

    bf16x8 kf[4][2];
#pragma unroll
    for (int mb = 0; mb < 4; mb++) {
      kf[mb][0] = *(const bf16x8*)&Ks[buf][(16 * mb + lm) * LK + qd * 8];
      kf[mb][1] = *(const bf16x8*)&Ks[buf][(16 * mb + lm) * LK + 32 + qd * 8];
    }

    f32x4 sc[4];
#pragma unroll
    for (int mb = 0; mb < 4; mb++) {
      f32x4 t = {};
      t = __builtin_amdgcn_mfma_f32_16x16x32_bf16(kf[mb][0], qf[0], t, 0, 0, 0);
      t = __builtin_amdgcn_mfma_f32_16x16x32_bf16(kf[mb][1], qf[1], t, 0, 0, 0);
      sc[mb] = t;
    }
    const int ib = s0 + 4 * qd + 127 - rowoff;
    float rs = 0.0f;
    unsigned wlo[4], whi[4];
#pragma unroll
    for (int mb = 0; mb < 4; mb++) {
      bf16x4 pk;
#pragma unroll
      for (int r = 0; r < 4; r++) {
        float p = __builtin_amdgcn_exp2f(sc[mb][r] + g * pbs[ib + 16 * mb + r]);
        rs += p;
        pk[r] = (bf16)p;
      }
      u32x2 pw = __builtin_bit_cast(u32x2, pk);
      wlo[mb] = pw[0]; whi[mb] = pw[1];
    }
    li += rs;
    bf16x8 pf[2];
    {
      unsigned a0 = wlo[0], b0v = wlo[1], a1 = whi[0], b1v = whi[1];
      qswap(a0, b0v);
      qswap(a1, b1v);
      u32x4 h0; h0[0] = a0; h0[1] = a1; h0[2] = b0v; h0[3] = b1v;
      pf[0] = __builtin_bit_cast(bf16x8, h0);
      unsigned c0 = wlo[2], d0v = wlo[3], c1 = whi[2], d1v = whi[3];
      qswap(c0, d0v);
      qswap(c1, d1v);
      u32x4 h1; h1[0] = c0; h1[1] = c1; h1[2] = d0v; h1[3] = d1v;
      pf[1] = __builtin_bit_cast(bf16x8, h1);
    }

#pragma unroll
    for (int db = 0; db < 4; db++) {
      bf16x8 vf0 = *(const bf16x8*)&Vs[buf][(16 * db + lm) * LK + qd * 8];
      bf16x8 vf1 = *(const bf16x8*)&Vs[buf][(16 * db + lm) * LK + 32 + qd * 8];
      o[db] = __builtin_amdgcn_mfma_f32_16x16x32_bf16(vf0, pf[0], o[db], 0, 0, 0);
      o[db] = __builtin_amdgcn_mfma_f32_16x16x32_bf16(vf1, pf[1], o[db], 0, 0, 0);
    }
    if (more) {
      *(bf16x8*)&Ks[buf ^ 1][srow * LK + scol] = nk0;
      *(bf16x8*)&Vs[buf ^ 1][srow * LK + scol] = nv0;
    }
    __syncthreads();
  }

  li += __shfl_xor(li, 16);
  li += __shfl_xor(li, 32);
  {
    const float inv = 1.0f / li;
    const int q = t0 + rowoff;
    bf16* obase = ctx + (size_t)(b * T_SEQ + q) * E_DIM + h * D_DIM + 4 * qd;
#pragma unroll
    for (int db = 0; db < 4; db++) {
      bf16x4 ov;
      ov[0] = (bf16)(o[db][0] * inv); ov[1] = (bf16)(o[db][1] * inv);
      ov[2] = (bf16)(o[db][2] * inv); ov[3] = (bf16)(o[db][3] * inv);
      *(bf16x4*)&obase[16 * db] = ov;
    }
  }
}

// ---------------- orchestration ----------------
extern "C" void kernel_launch(void* const* d_in, const int* in_sizes, int n_in,
                              void* d_out, int out_size, void* d_ws, size_t ws_size,
                              hipStream_t stream)
{
  const float* hs     = (const float*)d_in[0];
  const float* q_w    = (const float*)d_in[1];
  const float* q_b    = (const float*)d_in[2];
  const float* k_w    = (const float*)d_in[3];
  const float* k_b    = (const float*)d_in[4];
  const float* v_w    = (const float*)d_in[5];
  const float* v_b    = (const float*)d_in[6];
  const float* out_w  = (const float*)d_in[7];
  const float* out_b  = (const float*)d_in[8];
  const float* rel    = (const float*)d_in[9];
  const float* gconst = (const float*)d_in[10];
  const float* gru_w  = (const float*)d_in[11];
  const float* gru_b  = (const float*)d_in[12];

  char* p = (char*)d_ws;
  bf16* hsb  = (bf16*)p; p += (size_t)4096 * 1024 * 2;
  bf16* wcat = (bf16*)p; p += (size_t)3072 * 1024 * 2;
  bf16* wob  = (bf16*)p; p += (size_t)1024 * 1024 * 2;
  bf16* Qb   = (bf16*)p; p += (size_t)4096 * 1024 * 2;
  bf16* Kb   = (bf16*)p; p += (size_t)4096 * 1024 * 2;
  bf16* Vtb  = (bf16*)p; p += (size_t)2048 * 2048 * 2;
  bf16* ctxb = (bf16*)p; p += (size_t)4096 * 1024 * 2;
  float* gatep = (float*)p; p += (size_t)2 * H_NUM * T_SEQ * 4;
  float* pbt   = (float*)p; p += (size_t)H_NUM * NDELTA * 4;

  prep_kernel<<<8208, 256, 0, stream>>>(hs, hsb, gru_w, gru_b, gconst, gatep,
                                        q_w, k_w, v_w, out_w, wcat, wob, rel, pbt);

  const float qalpha = 0.125f * LOG2E;
  gemm2_kernel<1, 3072><<<768, 256, 0, stream>>>(
      hsb, wcat, q_b, k_b, v_b, qalpha, Qb, Kb, Vtb);

  attn3_kernel<<<512, 512, 0, stream>>>(Qb, Kb, Vtb, gatep, pbt, ctxb);

  gemm_o_kernel<<<512, 256, 0, stream>>>(ctxb, wob, out_b, (float*)d_out);
}

// Round 18
// 208.986 us; speedup vs baseline: 1.1137x; 1.0166x over previous
//
#include <hip/hip_runtime.h>
#include <hip/hip_bf16.h>
#include <math.h>

typedef __bf16 bf16;
typedef __bf16 bf16x4 __attribute__((ext_vector_type(4)));
typedef __bf16 bf16x8 __attribute__((ext_vector_type(8)));
typedef float  f32x4  __attribute__((ext_vector_type(4)));
typedef unsigned u32x2 __attribute__((ext_vector_type(2)));
typedef unsigned u32x4 __attribute__((ext_vector_type(4)));

#define T_SEQ 2048
#define E_DIM 1024
#define H_NUM 16
#define D_DIM 64
#define NDELTA 4095
#define LOG2E 1.4426950408889634f

__device__ __forceinline__ void gld16(const bf16* g, bf16* l) {
  __builtin_amdgcn_global_load_lds((__attribute__((address_space(1))) void*)(g),
                                   (__attribute__((address_space(3))) void*)(l), 16, 0, 0);
}

// in-register qd-group exchange via official gfx950 builtins
__device__ __forceinline__ void qswap(unsigned &a, unsigned &b) {
  u32x2 t  = __builtin_amdgcn_permlane32_swap(a, b, false, false);
  u32x2 t2 = __builtin_amdgcn_permlane16_swap(t[0], t[1], false, false);
  a = t2[0]; b = t2[1];
}

// ---------------- fused prep: hs-cast+gate | weight casts | pb table ----------------
__global__ __launch_bounds__(256)
void prep_kernel(const float* __restrict__ hs, bf16* __restrict__ hsb,
                 const float* __restrict__ gru_w, const float* __restrict__ gru_b,
                 const float* __restrict__ gconst, float* __restrict__ gate,
                 const float* __restrict__ q_w, const float* __restrict__ k_w,
                 const float* __restrict__ v_w, const float* __restrict__ o_w,
                 bf16* __restrict__ wcat, bf16* __restrict__ wob,
                 const float* __restrict__ rel_embed, float* __restrict__ pbt)
{
  __shared__ float w[512];
  const int bid = blockIdx.x;
  const int tid = threadIdx.x;

  if (bid < 4096) {
    // ---- hs cast + gate (one block per bt row) ----
    const int bt = bid;
    w[tid]       = gru_w[tid];
    w[tid + 256] = gru_w[tid + 256];
    __syncthreads();

    const int i = bt * 256 + tid;
    const float4 xv = reinterpret_cast<const float4*>(hs)[i];
    bf16x4 o;
    o[0] = (bf16)xv.x; o[1] = (bf16)xv.y; o[2] = (bf16)xv.z; o[3] = (bf16)xv.w;
    reinterpret_cast<bf16x4*>(hsb)[i] = o;

    const int h  = tid >> 4;
    const int d0 = (tid & 15) * 4;
    float acc[8];
#pragma unroll
    for (int e = 0; e < 8; e++) {
      acc[e] = xv.x * w[e*64+d0] + xv.y * w[e*64+d0+1]
             + xv.z * w[e*64+d0+2] + xv.w * w[e*64+d0+3];
    }
#pragma unroll
    for (int e = 0; e < 8; e++) {
      float v = acc[e];
      v += __shfl_xor(v, 1);
      v += __shfl_xor(v, 2);
      v += __shfl_xor(v, 4);
      v += __shfl_xor(v, 8);
      acc[e] = v;
    }
    if ((tid & 15) == 0) {
      float p0 = acc[0]+acc[1]+acc[2]+acc[3] + gru_b[0]+gru_b[1]+gru_b[2]+gru_b[3];
      float p1 = acc[4]+acc[5]+acc[6]+acc[7] + gru_b[4]+gru_b[5]+gru_b[6]+gru_b[7];
      float ga = 1.0f / (1.0f + expf(-p0));
      float gb = 1.0f / (1.0f + expf(-p1));
      float g = (ga * (gb * gconst[h] - 1.0f) + 2.0f) * LOG2E;
      int bb = bt >> 11;
      int t  = bt & (T_SEQ - 1);
      gate[((size_t)(bb * H_NUM + h)) * T_SEQ + t] = g;
    }
  } else if (bid < 8192) {
    // ---- weight casts: sel 0..3 over q/k/v/o ----
    const int wb  = bid - 4096;
    const int sel = wb >> 10;
    const int i   = (wb & 1023) * 256 + tid;
    const float* src = (sel == 0) ? q_w : (sel == 1) ? k_w : (sel == 2) ? v_w : o_w;
    bf16* dst = (sel < 3) ? (wcat + (size_t)sel * 1048576) : wob;
    const float4 v = reinterpret_cast<const float4*>(src)[i];
    bf16x4 o;
    o[0] = (bf16)v.x; o[1] = (bf16)v.y; o[2] = (bf16)v.z; o[3] = (bf16)v.w;
    reinterpret_cast<bf16x4*>(dst)[i] = o;
  } else {
    // ---- position-bias table (16 blocks) ----
    const int dd = (bid - 8192) * 256 + tid;
    if (dd >= NDELTA) return;
    int delta = dd - (T_SEQ - 1);
    int bucket = (delta > 0) ? 160 : 0;
    int rel = abs(delta);
    int v;
    if (rel < 80) {
      v = rel;
    } else {
      float rf = (float)(rel < 1 ? 1 : rel);
      float lf = logf(rf / 80.0f) * (80.0f / 2.302585092994046f);
      int lg = 80 + (int)lf;
      v = lg < 159 ? lg : 159;
    }
    bucket += v;
#pragma unroll
    for (int h = 0; h < H_NUM; h++)
      pbt[h * NDELTA + dd] = rel_embed[bucket * H_NUM + h];
  }
}

// ---------------- GEMM v3: BK=64 + XOR chunk swizzle + XCD-rectangle remap ----------------
template<int MODE, int N_TOTAL>
__global__ __launch_bounds__(256)
void gemm2_kernel(const bf16* __restrict__ A, const bf16* __restrict__ W,
                  const float* __restrict__ b0, const float* __restrict__ b1,
                  const float* __restrict__ b2, float qalpha,
                  void* __restrict__ out0, void* __restrict__ out1, void* __restrict__ out2)
{
  __shared__ bf16 As[128 * 64];
  __shared__ bf16 Bs[128 * 64];
  const int tid  = threadIdx.x;
  const int lane = tid & 63;
  const int wave = tid >> 6;
  // XCD-rectangle remap: xcd p covers n-blocks [(p&1)*12, +12), m-blocks [(p>>1)*8, +8)
  const int wid0  = blockIdx.x;          // 0..767
  const int xcd   = wid0 & 7;
  const int local = wid0 >> 3;           // 0..95
  const int nb_   = (xcd & 1) * 12 + (local % 12);
  const int mb_   = (xcd >> 1) * 8 + (local / 12);
  const int m0 = mb_ * 128;
  const int n0 = nb_ * 128;
  const int wm = (wave >> 1) * 64;
  const int wn = (wave & 1) * 64;
  const int qd = lane >> 4;
  const int lm = lane & 15;

  const int srow8  = lane >> 3;
  const int schunk = ((lane & 7) ^ srow8) * 8;
  const bf16* gA = A + (size_t)(m0 + wave * 32 + srow8) * 1024 + schunk;
  const bf16* gB = W + (size_t)(n0 + wave * 32 + srow8) * 1024 + schunk;
  bf16* lA = As + wave * 32 * 64;
  bf16* lB = Bs + wave * 32 * 64;

  f32x4 acc[4][4] = {};
  const int xs = lm & 7;

  for (int k0 = 0; k0 < 1024; k0 += 64) {
#pragma unroll
    for (int j = 0; j < 4; j++) {
      gld16(gA + (size_t)j * 8 * 1024 + k0, lA + j * 8 * 64);
      gld16(gB + (size_t)j * 8 * 1024 + k0, lB + j * 8 * 64);
    }
    __syncthreads();
    bf16x8 af[4][2], bfr[4][2];
#pragma unroll
    for (int i = 0; i < 4; i++) {
#pragma unroll
      for (int kk = 0; kk < 2; kk++) {
        af[i][kk]  = *(const bf16x8*)&As[(wm + i * 16 + lm) * 64 + (((kk * 4 + qd) ^ xs) * 8)];
        bfr[i][kk] = *(const bf16x8*)&Bs[(wn + i * 16 + lm) * 64 + (((kk * 4 + qd) ^ xs) * 8)];
      }
    }
#pragma unroll
    for (int kk = 0; kk < 2; kk++)
#pragma unroll
      for (int im = 0; im < 4; im++)
#pragma unroll
        for (int in = 0; in < 4; in++)
          acc[im][in] = __builtin_amdgcn_mfma_f32_16x16x32_bf16(af[im][kk], bfr[in][kk], acc[im][in], 0, 0, 0);
    __syncthreads();
  }

  const int seg = n0 >> 10;
  const float* bias = (MODE == 0) ? b0 : (seg == 0 ? b0 : (seg == 1 ? b1 : b2));
  const float alpha = (MODE == 1 && seg == 0) ? qalpha : 1.0f;

#pragma unroll
  for (int im = 0; im < 4; im++) {
#pragma unroll
    for (int in = 0; in < 4; in++) {
      const int n  = n0 + wn + in * 16 + lm;
      const int n1 = n & 1023;
      const float bv = bias[n1];
      const int mb = m0 + wm + im * 16 + qd * 4;
      if (MODE == 0) {
        float* o = (float*)out0;
#pragma unroll
        for (int r = 0; r < 4; r++)
          o[(size_t)(mb + r) * 1024 + n1] = acc[im][in][r] + bv;
      } else if (seg == 2) {
        const int bb = mb >> 11;
        const int t  = mb & 2047;
        bf16x4 pk;
#pragma unroll
        for (int r = 0; r < 4; r++) pk[r] = (bf16)(acc[im][in][r] + bv);
        *(bf16x4*)&((bf16*)out2)[((size_t)(bb * 1024 + n1)) * 2048 + t] = pk;
      } else {
        bf16* o = (bf16*)(seg == 0 ? out0 : out1);
#pragma unroll
        for (int r = 0; r < 4; r++)
          o[(size_t)(mb + r) * 1024 + n1] = (bf16)((acc[im][in][r] + bv) * alpha);
      }
    }
  }
}

// ---------------- O-projection GEMM v2: 64x128 tile, BK=64 + XOR swizzle + XCD remap ----------------
// Same proven transformation as gemm2 v3: halves barrier count (64 -> 32 per
// block), 16 MFMA per barrier window, conflict-free swizzled b128 frag reads.
__global__ __launch_bounds__(256)
void gemm_o_kernel(const bf16* __restrict__ A, const bf16* __restrict__ W,
                   const float* __restrict__ bias, float* __restrict__ out)
{
  __shared__ bf16 As[64 * 64];
  __shared__ bf16 Bs[128 * 64];
  const int tid  = threadIdx.x;
  const int lane = tid & 63;
  const int wave = tid >> 6;
  const int wid0  = blockIdx.x;          // 0..511
  const int xcd   = wid0 & 7;
  const int local = wid0 >> 3;           // 0..63
  const int n0 = (local & 7) * 128;
  const int m0 = (xcd * 8 + (local >> 3)) * 64;
  const int wm = (wave >> 1) * 32;
  const int wn = (wave & 1) * 64;
  const int qd = lane >> 4;
  const int lm = lane & 15;

  const int srow8  = lane >> 3;
  const int schunk = ((lane & 7) ^ srow8) * 8;
  // A: wave covers rows [wave*16, +16) -> 2 x 8-row groups
  const bf16* gA = A + (size_t)(m0 + wave * 16 + srow8) * 1024 + schunk;
  // B: wave covers rows [wave*32, +32) -> 4 x 8-row groups
  const bf16* gB = W + (size_t)(n0 + wave * 32 + srow8) * 1024 + schunk;
  bf16* lA = As + wave * 16 * 64;
  bf16* lB = Bs + wave * 32 * 64;

  f32x4 acc[2][4] = {};
  const int xs = lm & 7;

  for (int k0 = 0; k0 < 1024; k0 += 64) {
#pragma unroll
    for (int j = 0; j < 2; j++)
      gld16(gA + (size_t)j * 8 * 1024 + k0, lA + j * 8 * 64);
#pragma unroll
    for (int j = 0; j < 4; j++)
      gld16(gB + (size_t)j * 8 * 1024 + k0, lB + j * 8 * 64);
    __syncthreads();
    bf16x8 af[2][2], bfr[4][2];
#pragma unroll
    for (int i = 0; i < 2; i++)
#pragma unroll
      for (int kk = 0; kk < 2; kk++)
        af[i][kk] = *(const bf16x8*)&As[(wm + i * 16 + lm) * 64 + (((kk * 4 + qd) ^ xs) * 8)];
#pragma unroll
    for (int i = 0; i < 4; i++)
#pragma unroll
      for (int kk = 0; kk < 2; kk++)
        bfr[i][kk] = *(const bf16x8*)&Bs[(wn + i * 16 + lm) * 64 + (((kk * 4 + qd) ^ xs) * 8)];
#pragma unroll
    for (int kk = 0; kk < 2; kk++)
#pragma unroll
      for (int im = 0; im < 2; im++)
#pragma unroll
        for (int in = 0; in < 4; in++)
          acc[im][in] = __builtin_amdgcn_mfma_f32_16x16x32_bf16(af[im][kk], bfr[in][kk], acc[im][in], 0, 0, 0);
    __syncthreads();
  }

#pragma unroll
  for (int im = 0; im < 2; im++) {
#pragma unroll
    for (int in = 0; in < 4; in++) {
      const int n  = n0 + wn + in * 16 + lm;
      const float bv = bias[n];
      const int mb = m0 + wm + im * 16 + qd * 4;
#pragma unroll
      for (int r = 0; r < 4; r++)
        out[(size_t)(mb + r) * 1024 + n] = acc[im][in][r] + bv;
    }
  }
}

// ---------------- flash attention v7 + XCD-chunked block swizzle (best: 61.6 us) ----------------
#define LK 72
__global__ __launch_bounds__(512)
void attn3_kernel(const bf16* __restrict__ Qg, const bf16* __restrict__ Kg,
                  const bf16* __restrict__ Vtg, const float* __restrict__ gate,
                  const float* __restrict__ pbt, bf16* __restrict__ ctx)
{
  __shared__ bf16 Ks[2][64 * LK];
  __shared__ bf16 Vs[2][64 * LK];
  __shared__ float pbs[2176];

  const int wid0 = blockIdx.x;                       // 0..511 (hw linear)
  const int wid  = ((wid0 & 7) << 6) | (wid0 >> 3);  // XCD-chunked remap
  const int t0 = (wid & 15) * 128;
  const int h  = (wid >> 4) & 15;
  const int b  = wid >> 8;
  const int tid  = threadIdx.x;
  const int lane = tid & 63;
  const int wave = tid >> 6;        // 0..7
  const int qd = lane >> 4;
  const int lm = lane & 15;

  for (int i = tid; i < 2176; i += 512) {
    int idx = i - t0 + 1920;
    pbs[i] = (idx >= 0 && idx < NDELTA) ? pbt[h * NDELTA + idx] : 0.0f;
  }

  const int rowoff = wave * 16 + lm;
  bf16x8 qf[2];
  float g;
  {
    const int q = t0 + rowoff;
    const bf16* qrow = Qg + (size_t)(b * T_SEQ + q) * E_DIM + h * D_DIM;
    qf[0] = *(const bf16x8*)(qrow + qd * 8);
    qf[1] = *(const bf16x8*)(qrow + 32 + qd * 8);
    g = gate[((size_t)(b * H_NUM + h)) * T_SEQ + q];
  }

  const int srow = tid >> 3;
  const int scol = (tid & 7) * 8;
  const bf16* kgp = Kg  + ((size_t)(b * T_SEQ) + srow) * E_DIM + h * D_DIM + scol;
  const bf16* vgp = Vtg + ((size_t)(b * 1024) + h * D_DIM + srow) * T_SEQ + scol;

  {
    bf16x8 a0 = *(const bf16x8*)kgp;
    bf16x8 c0 = *(const bf16x8*)vgp;
    *(bf16x8*)&Ks[0][srow * LK + scol] = a0;
    *(bf16x8*)&Vs[0][srow * LK + scol] = c0;
  }
  __syncthreads();

  f32x4 o[4] = {};
  float li = 0.0f;

  for (int it = 0; it < T_SEQ / 64; it++) {
    const int s0 = it * 64;
    const int buf = it & 1;
    const bool more = (it + 1 < T_SEQ / 64);
    bf16x8 nk0, nv0;
    if (more) {
      nk0 = *(const bf16x8*)(kgp + (size_t)(s0 + 64) * E_DIM);
      nv0 = *(const bf16x8*)(vgp + (s0 + 64));
    }

    bf16x8 kf[4][2];
#pragma unroll
    for (int mb = 0; mb < 4; mb++) {
      kf[mb][0] = *(const bf16x8*)&Ks[buf][(16 * mb + lm) * LK + qd * 8];
      kf[mb][1] = *(const bf16x8*)&Ks[buf][(16 * mb + lm) * LK + 32 + qd * 8];
    }

    f32x4 sc[4];
#pragma unroll
    for (int mb = 0; mb < 4; mb++) {
      f32x4 t = {};
      t = __builtin_amdgcn_mfma_f32_16x16x32_bf16(kf[mb][0], qf[0], t, 0, 0, 0);
      t = __builtin_amdgcn_mfma_f32_16x16x32_bf16(kf[mb][1], qf[1], t, 0, 0, 0);
      sc[mb] = t;
    }
    const int ib = s0 + 4 * qd + 127 - rowoff;
    float rs = 0.0f;
    unsigned wlo[4], whi[4];
#pragma unroll
    for (int mb = 0; mb < 4; mb++) {
      bf16x4 pk;
#pragma unroll
      for (int r = 0; r < 4; r++) {
        float p = __builtin_amdgcn_exp2f(sc[mb][r] + g * pbs[ib + 16 * mb + r]);
        rs += p;
        pk[r] = (bf16)p;
      }
      u32x2 pw = __builtin_bit_cast(u32x2, pk);
      wlo[mb] = pw[0]; whi[mb] = pw[1];
    }
    li += rs;
    bf16x8 pf[2];
    {
      unsigned a0 = wlo[0], b0v = wlo[1], a1 = whi[0], b1v = whi[1];
      qswap(a0, b0v);
      qswap(a1, b1v);
      u32x4 h0; h0[0] = a0; h0[1] = a1; h0[2] = b0v; h0[3] = b1v;
      pf[0] = __builtin_bit_cast(bf16x8, h0);
      unsigned c0 = wlo[2], d0v = wlo[3], c1 = whi[2], d1v = whi[3];
      qswap(c0, d0v);
      qswap(c1, d1v);
      u32x4 h1; h1[0] = c0; h1[1] = c1; h1[2] = d0v; h1[3] = d1v;
      pf[1] = __builtin_bit_cast(bf16x8, h1);
    }

#pragma unroll
    for (int db = 0; db < 4; db++) {
      bf16x8 vf0 = *(const bf16x8*)&Vs[buf][(16 * db + lm) * LK + qd * 8];
      bf16x8 vf1 = *(const bf16x8*)&Vs[buf][(16 * db + lm) * LK + 32 + qd * 8];
      o[db] = __builtin_amdgcn_mfma_f32_16x16x32_bf16(vf0, pf[0], o[db], 0, 0, 0);
      o[db] = __builtin_amdgcn_mfma_f32_16x16x32_bf16(vf1, pf[1], o[db], 0, 0, 0);
    }
    if (more) {
      *(bf16x8*)&Ks[buf ^ 1][srow * LK + scol] = nk0;
      *(bf16x8*)&Vs[buf ^ 1][srow * LK + scol] = nv0;
    }
    __syncthreads();
  }

  li += __shfl_xor(li, 16);
  li += __shfl_xor(li, 32);
  {
    const float inv = 1.0f / li;
    const int q = t0 + rowoff;
    bf16* obase = ctx + (size_t)(b * T_SEQ + q) * E_DIM + h * D_DIM + 4 * qd;
#pragma unroll
    for (int db = 0; db < 4; db++) {
      bf16x4 ov;
      ov[0] = (bf16)(o[db][0] * inv); ov[1] = (bf16)(o[db][1] * inv);
      ov[2] = (bf16)(o[db][2] * inv); ov[3] = (bf16)(o[db][3] * inv);
      *(bf16x4*)&obase[16 * db] = ov;
    }
  }
}

// ---------------- orchestration ----------------
extern "C" void kernel_launch(void* const* d_in, const int* in_sizes, int n_in,
                              void* d_out, int out_size, void* d_ws, size_t ws_size,
                              hipStream_t stream)
{
  const float* hs     = (const float*)d_in[0];
  const float* q_w    = (const float*)d_in[1];
  const float* q_b    = (const float*)d_in[2];
  const float* k_w    = (const float*)d_in[3];
  const float* k_b    = (const float*)d_in[4];
  const float* v_w    = (const float*)d_in[5];
  const float* v_b    = (const float*)d_in[6];
  const float* out_w  = (const float*)d_in[7];
  const float* out_b  = (const float*)d_in[8];
  const float* rel    = (const float*)d_in[9];
  const float* gconst = (const float*)d_in[10];
  const float* gru_w  = (const float*)d_in[11];
  const float* gru_b  = (const float*)d_in[12];

  char* p = (char*)d_ws;
  bf16* hsb  = (bf16*)p; p += (size_t)4096 * 1024 * 2;
  bf16* wcat = (bf16*)p; p += (size_t)3072 * 1024 * 2;
  bf16* wob  = (bf16*)p; p += (size_t)1024 * 1024 * 2;
  bf16* Qb   = (bf16*)p; p += (size_t)4096 * 1024 * 2;
  bf16* Kb   = (bf16*)p; p += (size_t)4096 * 1024 * 2;
  bf16* Vtb  = (bf16*)p; p += (size_t)2048 * 2048 * 2;
  bf16* ctxb = (bf16*)p; p += (size_t)4096 * 1024 * 2;
  float* gatep = (float*)p; p += (size_t)2 * H_NUM * T_SEQ * 4;
  float* pbt   = (float*)p; p += (size_t)H_NUM * NDELTA * 4;

  prep_kernel<<<8208, 256, 0, stream>>>(hs, hsb, gru_w, gru_b, gconst, gatep,
                                        q_w, k_w, v_w, out_w, wcat, wob, rel, pbt);

  const float qalpha = 0.125f * LOG2E;
  gemm2_kernel<1, 3072><<<768, 256, 0, stream>>>(
      hsb, wcat, q_b, k_b, v_b, qalpha, Qb, Kb, Vtb);

  attn3_kernel<<<512, 512, 0, stream>>>(Qb, Kb, Vtb, gatep, pbt, ctxb);

  gemm_o_kernel<<<512, 256, 0, stream>>>(ctxb, wob, out_b, (float*)d_out);
}

// Round 19
// 204.500 us; speedup vs baseline: 1.1381x; 1.0219x over previous
//
#include <hip/hip_runtime.h>
#include <hip/hip_bf16.h>
#include <math.h>

typedef __bf16 bf16;
typedef __bf16 bf16x4 __attribute__((ext_vector_type(4)));
typedef __bf16 bf16x8 __attribute__((ext_vector_type(8)));
typedef float  f32x4  __attribute__((ext_vector_type(4)));
typedef unsigned u32x2 __attribute__((ext_vector_type(2)));
typedef unsigned u32x4 __attribute__((ext_vector_type(4)));

#define T_SEQ 2048
#define E_DIM 1024
#define H_NUM 16
#define D_DIM 64
#define NDELTA 4095
#define LOG2E 1.4426950408889634f

__device__ __forceinline__ void gld16(const bf16* g, bf16* l) {
  __builtin_amdgcn_global_load_lds((__attribute__((address_space(1))) void*)(g),
                                   (__attribute__((address_space(3))) void*)(l), 16, 0, 0);
}

// in-register qd-group exchange via official gfx950 builtins
__device__ __forceinline__ void qswap(unsigned &a, unsigned &b) {
  u32x2 t  = __builtin_amdgcn_permlane32_swap(a, b, false, false);
  u32x2 t2 = __builtin_amdgcn_permlane16_swap(t[0], t[1], false, false);
  a = t2[0]; b = t2[1];
}

// ---------------- fused prep: hs-cast+gate | weight casts | pb table ----------------
__global__ __launch_bounds__(256)
void prep_kernel(const float* __restrict__ hs, bf16* __restrict__ hsb,
                 const float* __restrict__ gru_w, const float* __restrict__ gru_b,
                 const float* __restrict__ gconst, float* __restrict__ gate,
                 const float* __restrict__ q_w, const float* __restrict__ k_w,
                 const float* __restrict__ v_w, const float* __restrict__ o_w,
                 bf16* __restrict__ wcat, bf16* __restrict__ wob,
                 const float* __restrict__ rel_embed, float* __restrict__ pbt)
{
  __shared__ float w[512];
  const int bid = blockIdx.x;
  const int tid = threadIdx.x;

  if (bid < 4096) {
    // ---- hs cast + gate (one block per bt row) ----
    const int bt = bid;
    w[tid]       = gru_w[tid];
    w[tid + 256] = gru_w[tid + 256];
    __syncthreads();

    const int i = bt * 256 + tid;
    const float4 xv = reinterpret_cast<const float4*>(hs)[i];
    bf16x4 o;
    o[0] = (bf16)xv.x; o[1] = (bf16)xv.y; o[2] = (bf16)xv.z; o[3] = (bf16)xv.w;
    reinterpret_cast<bf16x4*>(hsb)[i] = o;

    const int h  = tid >> 4;
    const int d0 = (tid & 15) * 4;
    float acc[8];
#pragma unroll
    for (int e = 0; e < 8; e++) {
      acc[e] = xv.x * w[e*64+d0] + xv.y * w[e*64+d0+1]
             + xv.z * w[e*64+d0+2] + xv.w * w[e*64+d0+3];
    }
#pragma unroll
    for (int e = 0; e < 8; e++) {
      float v = acc[e];
      v += __shfl_xor(v, 1);
      v += __shfl_xor(v, 2);
      v += __shfl_xor(v, 4);
      v += __shfl_xor(v, 8);
      acc[e] = v;
    }
    if ((tid & 15) == 0) {
      float p0 = acc[0]+acc[1]+acc[2]+acc[3] + gru_b[0]+gru_b[1]+gru_b[2]+gru_b[3];
      float p1 = acc[4]+acc[5]+acc[6]+acc[7] + gru_b[4]+gru_b[5]+gru_b[6]+gru_b[7];
      float ga = 1.0f / (1.0f + expf(-p0));
      float gb = 1.0f / (1.0f + expf(-p1));
      float g = (ga * (gb * gconst[h] - 1.0f) + 2.0f) * LOG2E;
      int bb = bt >> 11;
      int t  = bt & (T_SEQ - 1);
      gate[((size_t)(bb * H_NUM + h)) * T_SEQ + t] = g;
    }
  } else if (bid < 8192) {
    // ---- weight casts: sel 0..3 over q/k/v/o ----
    const int wb  = bid - 4096;
    const int sel = wb >> 10;
    const int i   = (wb & 1023) * 256 + tid;
    const float* src = (sel == 0) ? q_w : (sel == 1) ? k_w : (sel == 2) ? v_w : o_w;
    bf16* dst = (sel < 3) ? (wcat + (size_t)sel * 1048576) : wob;
    const float4 v = reinterpret_cast<const float4*>(src)[i];
    bf16x4 o;
    o[0] = (bf16)v.x; o[1] = (bf16)v.y; o[2] = (bf16)v.z; o[3] = (bf16)v.w;
    reinterpret_cast<bf16x4*>(dst)[i] = o;
  } else {
    // ---- position-bias table (16 blocks) ----
    const int dd = (bid - 8192) * 256 + tid;
    if (dd >= NDELTA) return;
    int delta = dd - (T_SEQ - 1);
    int bucket = (delta > 0) ? 160 : 0;
    int rel = abs(delta);
    int v;
    if (rel < 80) {
      v = rel;
    } else {
      float rf = (float)(rel < 1 ? 1 : rel);
      float lf = logf(rf / 80.0f) * (80.0f / 2.302585092994046f);
      int lg = 80 + (int)lf;
      v = lg < 159 ? lg : 159;
    }
    bucket += v;
#pragma unroll
    for (int h = 0; h < H_NUM; h++)
      pbt[h * NDELTA + dd] = rel_embed[bucket * H_NUM + h];
  }
}

// ---------------- QKV GEMM v4: 64x128 tile, BK=64 + XOR swizzle, 6 blocks/CU ----------------
// r18's winning gemm_o structure applied to the fused QKV (4096 x 3072 x 1024):
// grid 1536 = 6/CU doubles waves/CU (12 -> 24) vs the 128^2 3/CU variant.
// XCD rectangle: 1536 = 8 x (12n x 16m); per-XCD 3 MB W + 2 MB A (L2-fit).
// n0 multiple of 128 divides 1024 -> segment routing stays block-uniform.
__global__ __launch_bounds__(256)
void gemm_qkv_kernel(const bf16* __restrict__ A, const bf16* __restrict__ W,
                     const float* __restrict__ b0, const float* __restrict__ b1,
                     const float* __restrict__ b2, float qalpha,
                     void* __restrict__ out0, void* __restrict__ out1, void* __restrict__ out2)
{
  __shared__ bf16 As[64 * 64];
  __shared__ bf16 Bs[128 * 64];
  const int tid  = threadIdx.x;
  const int lane = tid & 63;
  const int wave = tid >> 6;
  const int wid0  = blockIdx.x;          // 0..1535
  const int xcd   = wid0 & 7;
  const int local = wid0 >> 3;           // 0..191
  const int nb_   = (xcd & 1) * 12 + (local % 12);   // 0..23
  const int mb_   = (xcd >> 1) * 16 + (local / 12);  // 0..63
  const int m0 = mb_ * 64;
  const int n0 = nb_ * 128;
  const int wm = (wave >> 1) * 32;
  const int wn = (wave & 1) * 64;
  const int qd = lane >> 4;
  const int lm = lane & 15;

  const int srow8  = lane >> 3;
  const int schunk = ((lane & 7) ^ srow8) * 8;
  // A: wave covers rows [wave*16, +16) -> 2 x 8-row groups
  const bf16* gA = A + (size_t)(m0 + wave * 16 + srow8) * 1024 + schunk;
  // B: wave covers rows [wave*32, +32) -> 4 x 8-row groups
  const bf16* gB = W + (size_t)(n0 + wave * 32 + srow8) * 1024 + schunk;
  bf16* lA = As + wave * 16 * 64;
  bf16* lB = Bs + wave * 32 * 64;

  f32x4 acc[2][4] = {};
  const int xs = lm & 7;

  for (int k0 = 0; k0 < 1024; k0 += 64) {
#pragma unroll
    for (int j = 0; j < 2; j++)
      gld16(gA + (size_t)j * 8 * 1024 + k0, lA + j * 8 * 64);
#pragma unroll
    for (int j = 0; j < 4; j++)
      gld16(gB + (size_t)j * 8 * 1024 + k0, lB + j * 8 * 64);
    __syncthreads();
    bf16x8 af[2][2], bfr[4][2];
#pragma unroll
    for (int i = 0; i < 2; i++)
#pragma unroll
      for (int kk = 0; kk < 2; kk++)
        af[i][kk] = *(const bf16x8*)&As[(wm + i * 16 + lm) * 64 + (((kk * 4 + qd) ^ xs) * 8)];
#pragma unroll
    for (int i = 0; i < 4; i++)
#pragma unroll
      for (int kk = 0; kk < 2; kk++)
        bfr[i][kk] = *(const bf16x8*)&Bs[(wn + i * 16 + lm) * 64 + (((kk * 4 + qd) ^ xs) * 8)];
#pragma unroll
    for (int kk = 0; kk < 2; kk++)
#pragma unroll
      for (int im = 0; im < 2; im++)
#pragma unroll
        for (int in = 0; in < 4; in++)
          acc[im][in] = __builtin_amdgcn_mfma_f32_16x16x32_bf16(af[im][kk], bfr[in][kk], acc[im][in], 0, 0, 0);
    __syncthreads();
  }

  const int seg = n0 >> 10;               // block-uniform (n0 multiple of 128)
  const float* bias = (seg == 0) ? b0 : (seg == 1 ? b1 : b2);
  const float alpha = (seg == 0) ? qalpha : 1.0f;

#pragma unroll
  for (int im = 0; im < 2; im++) {
#pragma unroll
    for (int in = 0; in < 4; in++) {
      const int n  = n0 + wn + in * 16 + lm;
      const int n1 = n & 1023;
      const float bv = bias[n1];
      const int mb = m0 + wm + im * 16 + qd * 4;
      if (seg == 2) {
        // Vt layout: row = b*1024 + n1, col = t
        const int bb = mb >> 11;
        const int t  = mb & 2047;
        bf16x4 pk;
#pragma unroll
        for (int r = 0; r < 4; r++) pk[r] = (bf16)(acc[im][in][r] + bv);
        *(bf16x4*)&((bf16*)out2)[((size_t)(bb * 1024 + n1)) * 2048 + t] = pk;
      } else {
        bf16* o = (bf16*)(seg == 0 ? out0 : out1);
#pragma unroll
        for (int r = 0; r < 4; r++)
          o[(size_t)(mb + r) * 1024 + n1] = (bf16)((acc[im][in][r] + bv) * alpha);
      }
    }
  }
}

// ---------------- O-projection GEMM v2: 64x128 tile, BK=64 + XOR swizzle + XCD remap ----------------
__global__ __launch_bounds__(256)
void gemm_o_kernel(const bf16* __restrict__ A, const bf16* __restrict__ W,
                   const float* __restrict__ bias, float* __restrict__ out)
{
  __shared__ bf16 As[64 * 64];
  __shared__ bf16 Bs[128 * 64];
  const int tid  = threadIdx.x;
  const int lane = tid & 63;
  const int wave = tid >> 6;
  const int wid0  = blockIdx.x;          // 0..511
  const int xcd   = wid0 & 7;
  const int local = wid0 >> 3;           // 0..63
  const int n0 = (local & 7) * 128;
  const int m0 = (xcd * 8 + (local >> 3)) * 64;
  const int wm = (wave >> 1) * 32;
  const int wn = (wave & 1) * 64;
  const int qd = lane >> 4;
  const int lm = lane & 15;

  const int srow8  = lane >> 3;
  const int schunk = ((lane & 7) ^ srow8) * 8;
  const bf16* gA = A + (size_t)(m0 + wave * 16 + srow8) * 1024 + schunk;
  const bf16* gB = W + (size_t)(n0 + wave * 32 + srow8) * 1024 + schunk;
  bf16* lA = As + wave * 16 * 64;
  bf16* lB = Bs + wave * 32 * 64;

  f32x4 acc[2][4] = {};
  const int xs = lm & 7;

  for (int k0 = 0; k0 < 1024; k0 += 64) {
#pragma unroll
    for (int j = 0; j < 2; j++)
      gld16(gA + (size_t)j * 8 * 1024 + k0, lA + j * 8 * 64);
#pragma unroll
    for (int j = 0; j < 4; j++)
      gld16(gB + (size_t)j * 8 * 1024 + k0, lB + j * 8 * 64);
    __syncthreads();
    bf16x8 af[2][2], bfr[4][2];
#pragma unroll
    for (int i = 0; i < 2; i++)
#pragma unroll
      for (int kk = 0; kk < 2; kk++)
        af[i][kk] = *(const bf16x8*)&As[(wm + i * 16 + lm) * 64 + (((kk * 4 + qd) ^ xs) * 8)];
#pragma unroll
    for (int i = 0; i < 4; i++)
#pragma unroll
      for (int kk = 0; kk < 2; kk++)
        bfr[i][kk] = *(const bf16x8*)&Bs[(wn + i * 16 + lm) * 64 + (((kk * 4 + qd) ^ xs) * 8)];
#pragma unroll
    for (int kk = 0; kk < 2; kk++)
#pragma unroll
      for (int im = 0; im < 2; im++)
#pragma unroll
        for (int in = 0; in < 4; in++)
          acc[im][in] = __builtin_amdgcn_mfma_f32_16x16x32_bf16(af[im][kk], bfr[in][kk], acc[im][in], 0, 0, 0);
    __syncthreads();
  }

#pragma unroll
  for (int im = 0; im < 2; im++) {
#pragma unroll
    for (int in = 0; in < 4; in++) {
      const int n  = n0 + wn + in * 16 + lm;
      const float bv = bias[n];
      const int mb = m0 + wm + im * 16 + qd * 4;
#pragma unroll
      for (int r = 0; r < 4; r++)
        out[(size_t)(mb + r) * 1024 + n] = acc[im][in][r] + bv;
    }
  }
}

// ---------------- flash attention v7 + XCD-chunked block swizzle (best: 61.6 us) ----------------
#define LK 72
__global__ __launch_bounds__(512)
void attn3_kernel(const bf16* __restrict__ Qg, const bf16* __restrict__ Kg,
                  const bf16* __restrict__ Vtg, const float* __restrict__ gate,
                  const float* __restrict__ pbt, bf16* __restrict__ ctx)
{
  __shared__ bf16 Ks[2][64 * LK];
  __shared__ bf16 Vs[2][64 * LK];
  __shared__ float pbs[2176];

  const int wid0 = blockIdx.x;                       // 0..511 (hw linear)
  const int wid  = ((wid0 & 7) << 6) | (wid0 >> 3);  // XCD-chunked remap
  const int t0 = (wid & 15) * 128;
  const int h  = (wid >> 4) & 15;
  const int b  = wid >> 8;
  const int tid  = threadIdx.x;
  const int lane = tid & 63;
  const int wave = tid >> 6;        // 0..7
  const int qd = lane >> 4;
  const int lm = lane & 15;

  for (int i = tid; i < 2176; i += 512) {
    int idx = i - t0 + 1920;
    pbs[i] = (idx >= 0 && idx < NDELTA) ? pbt[h * NDELTA + idx] : 0.0f;
  }

  const int rowoff = wave * 16 + lm;
  bf16x8 qf[2];
  float g;
  {
    const int q = t0 + rowoff;
    const bf16* qrow = Qg + (size_t)(b * T_SEQ + q) * E_DIM + h * D_DIM;
    qf[0] = *(const bf16x8*)(qrow + qd * 8);
    qf[1] = *(const bf16x8*)(qrow + 32 + qd * 8);
    g = gate[((size_t)(b * H_NUM + h)) * T_SEQ + q];
  }

  const int srow = tid >> 3;
  const int scol = (tid & 7) * 8;
  const bf16* kgp = Kg  + ((size_t)(b * T_SEQ) + srow) * E_DIM + h * D_DIM + scol;
  const bf16* vgp = Vtg + ((size_t)(b * 1024) + h * D_DIM + srow) * T_SEQ + scol;

  {
    bf16x8 a0 = *(const bf16x8*)kgp;
    bf16x8 c0 = *(const bf16x8*)vgp;
    *(bf16x8*)&Ks[0][srow * LK + scol] = a0;
    *(bf16x8*)&Vs[0][srow * LK + scol] = c0;
  }
  __syncthreads();

  f32x4 o[4] = {};
  float li = 0.0f;

  for (int it = 0; it < T_SEQ / 64; it++) {
    const int s0 = it * 64;
    const int buf = it & 1;
    const bool more = (it + 1 < T_SEQ / 64);
    bf16x8 nk0, nv0;
    if (more) {
      nk0 = *(const bf16x8*)(kgp + (size_t)(s0 + 64) * E_DIM);
      nv0 = *(const bf16x8*)(vgp + (s0 + 64));
    }

    bf16x8 kf[4][2];
#pragma unroll
    for (int mb = 0; mb < 4; mb++) {
      kf[mb][0] = *(const bf16x8*)&Ks[buf][(16 * mb + lm) * LK + qd * 8];
      kf[mb][1] = *(const bf16x8*)&Ks[buf][(16 * mb + lm) * LK + 32 + qd * 8];
    }

    f32x4 sc[4];
#pragma unroll
    for (int mb = 0; mb < 4; mb++) {
      f32x4 t = {};
      t = __builtin_amdgcn_mfma_f32_16x16x32_bf16(kf[mb][0], qf[0], t, 0, 0, 0);
      t = __builtin_amdgcn_mfma_f32_16x16x32_bf16(kf[mb][1], qf[1], t, 0, 0, 0);
      sc[mb] = t;
    }
    const int ib = s0 + 4 * qd + 127 - rowoff;
    float rs = 0.0f;
    unsigned wlo[4], whi[4];
#pragma unroll
    for (int mb = 0; mb < 4; mb++) {
      bf16x4 pk;
#pragma unroll
      for (int r = 0; r < 4; r++) {
        float p = __builtin_amdgcn_exp2f(sc[mb][r] + g * pbs[ib + 16 * mb + r]);
        rs += p;
        pk[r] = (bf16)p;
      }
      u32x2 pw = __builtin_bit_cast(u32x2, pk);
      wlo[mb] = pw[0]; whi[mb] = pw[1];
    }
    li += rs;
    bf16x8 pf[2];
    {
      unsigned a0 = wlo[0], b0v = wlo[1], a1 = whi[0], b1v = whi[1];
      qswap(a0, b0v);
      qswap(a1, b1v);
      u32x4 h0; h0[0] = a0; h0[1] = a1; h0[2] = b0v; h0[3] = b1v;
      pf[0] = __builtin_bit_cast(bf16x8, h0);
      unsigned c0 = wlo[2], d0v = wlo[3], c1 = whi[2], d1v = whi[3];
      qswap(c0, d0v);
      qswap(c1, d1v);
      u32x4 h1; h1[0] = c0; h1[1] = c1; h1[2] = d0v; h1[3] = d1v;
      pf[1] = __builtin_bit_cast(bf16x8, h1);
    }

#pragma unroll
    for (int db = 0; db < 4; db++) {
      bf16x8 vf0 = *(const bf16x8*)&Vs[buf][(16 * db + lm) * LK + qd * 8];
      bf16x8 vf1 = *(const bf16x8*)&Vs[buf][(16 * db + lm) * LK + 32 + qd * 8];
      o[db] = __builtin_amdgcn_mfma_f32_16x16x32_bf16(vf0, pf[0], o[db], 0, 0, 0);
      o[db] = __builtin_amdgcn_mfma_f32_16x16x32_bf16(vf1, pf[1], o[db], 0, 0, 0);
    }
    if (more) {
      *(bf16x8*)&Ks[buf ^ 1][srow * LK + scol] = nk0;
      *(bf16x8*)&Vs[buf ^ 1][srow * LK + scol] = nv0;
    }
    __syncthreads();
  }

  li += __shfl_xor(li, 16);
  li += __shfl_xor(li, 32);
  {
    const float inv = 1.0f / li;
    const int q = t0 + rowoff;
    bf16* obase = ctx + (size_t)(b * T_SEQ + q) * E_DIM + h * D_DIM + 4 * qd;
#pragma unroll
    for (int db = 0; db < 4; db++) {
      bf16x4 ov;
      ov[0] = (bf16)(o[db][0] * inv); ov[1] = (bf16)(o[db][1] * inv);
      ov[2] = (bf16)(o[db][2] * inv); ov[3] = (bf16)(o[db][3] * inv);
      *(bf16x4*)&obase[16 * db] = ov;
    }
  }
}

// ---------------- orchestration ----------------
extern "C" void kernel_launch(void* const* d_in, const int* in_sizes, int n_in,
                              void* d_out, int out_size, void* d_ws, size_t ws_size,
                              hipStream_t stream)
{
  const float* hs     = (const float*)d_in[0];
  const float* q_w    = (const float*)d_in[1];
  const float* q_b    = (const float*)d_in[2];
  const float* k_w    = (const float*)d_in[3];
  const float* k_b    = (const float*)d_in[4];
  const float* v_w    = (const float*)d_in[5];
  const float* v_b    = (const float*)d_in[6];
  const float* out_w  = (const float*)d_in[7];
  const float* out_b  = (const float*)d_in[8];
  const float* rel    = (const float*)d_in[9];
  const float* gconst = (const float*)d_in[10];
  const float* gru_w  = (const float*)d_in[11];
  const float* gru_b  = (const float*)d_in[12];

  char* p = (char*)d_ws;
  bf16* hsb  = (bf16*)p; p += (size_t)4096 * 1024 * 2;
  bf16* wcat = (bf16*)p; p += (size_t)3072 * 1024 * 2;
  bf16* wob  = (bf16*)p; p += (size_t)1024 * 1024 * 2;
  bf16* Qb   = (bf16*)p; p += (size_t)4096 * 1024 * 2;
  bf16* Kb   = (bf16*)p; p += (size_t)4096 * 1024 * 2;
  bf16* Vtb  = (bf16*)p; p += (size_t)2048 * 2048 * 2;
  bf16* ctxb = (bf16*)p; p += (size_t)4096 * 1024 * 2;
  float* gatep = (float*)p; p += (size_t)2 * H_NUM * T_SEQ * 4;
  float* pbt   = (float*)p; p += (size_t)H_NUM * NDELTA * 4;

  prep_kernel<<<8208, 256, 0, stream>>>(hs, hsb, gru_w, gru_b, gconst, gatep,
                                        q_w, k_w, v_w, out_w, wcat, wob, rel, pbt);

  const float qalpha = 0.125f * LOG2E;
  gemm_qkv_kernel<<<1536, 256, 0, stream>>>(
      hsb, wcat, q_b, k_b, v_b, qalpha, Qb, Kb, Vtb);

  attn3_kernel<<<512, 512, 0, stream>>>(Qb, Kb, Vtb, gatep, pbt, ctxb);

  gemm_o_kernel<<<512, 256, 0, stream>>>(ctxb, wob, out_b, (float*)d_out);
}